// Round 3
// baseline (2159.634 us; speedup 1.0000x reference)
//
#include <hip/hip_runtime.h>
#include <math.h>

#define B_ 64
#define T_ 128
#define INDIM 300
#define D_ 64
#define C_ 10
#define BETA_ 0.8f

typedef unsigned int u32;
typedef _Float16 half8 __attribute__((ext_vector_type(8)));
typedef float f32x4 __attribute__((ext_vector_type(4)));
typedef u32 u32x4 __attribute__((ext_vector_type(4)));
typedef u32 u32x2 __attribute__((ext_vector_type(2)));

// fragment-group index: cb = 16-col block, kc = 32-k block
#define GIDX(cb,kc,ln) ((((cb)*2+(kc))*64) + (ln))

struct Frag { half8 h, l; };

static __device__ __forceinline__ float sigmoidf_(float x){ return 1.f/(1.f+expf(-x)); }

static __device__ __forceinline__ float wave_sum(float v){
#pragma unroll
  for (int off = 32; off > 0; off >>= 1) v += __shfl_down(v, off);
  return v;
}

static __device__ __forceinline__ u32 pkh(_Float16 a, _Float16 b){
  unsigned short ba = __builtin_bit_cast(unsigned short, a);
  unsigned short bb = __builtin_bit_cast(unsigned short, b);
  return (u32)ba | ((u32)bb << 16);
}

static __device__ __forceinline__ void split4(const float* x, u32x2& hw, u32x2& lw){
  _Float16 h0=(_Float16)x[0], h1=(_Float16)x[1], h2=(_Float16)x[2], h3=(_Float16)x[3];
  _Float16 l0=(_Float16)(x[0]-(float)h0), l1=(_Float16)(x[1]-(float)h1);
  _Float16 l2=(_Float16)(x[2]-(float)h2), l3=(_Float16)(x[3]-(float)h3);
  hw[0]=pkh(h0,h1); hw[1]=pkh(h2,h3); lw[0]=pkh(l0,l1); lw[1]=pkh(l2,l3);
}

static __device__ __forceinline__ void up2v(u32 hw, u32 lw, float& v0, float& v1){
  _Float16 h0=__builtin_bit_cast(_Float16,(unsigned short)(hw & 0xffffu));
  _Float16 h1=__builtin_bit_cast(_Float16,(unsigned short)(hw >> 16));
  _Float16 l0=__builtin_bit_cast(_Float16,(unsigned short)(lw & 0xffffu));
  _Float16 l1=__builtin_bit_cast(_Float16,(unsigned short)(lw >> 16));
  v0 = (float)h0 + (float)l0;
  v1 = (float)h1 + (float)l1;
}

static __device__ __forceinline__ void mfma4(const Frag& a, const Frag& b, f32x4& acc){
  acc = __builtin_amdgcn_mfma_f32_16x16x32_f16(a.h, b.h, acc, 0, 0, 0);
  acc = __builtin_amdgcn_mfma_f32_16x16x32_f16(a.h, b.l, acc, 0, 0, 0);
  acc = __builtin_amdgcn_mfma_f32_16x16x32_f16(a.l, b.h, acc, 0, 0, 0);
  acc = __builtin_amdgcn_mfma_f32_16x16x32_f16(a.l, b.l, acc, 0, 0, 0);
}

static __device__ __forceinline__ Frag ldfrag(const u32* buf, int g, bool neg){
  u32x4 a = *reinterpret_cast<const u32x4*>(buf + g*4);
  u32x4 b = *reinterpret_cast<const u32x4*>(buf + 2048 + g*4);
  if (neg){
#pragma unroll
    for (int i=0;i<4;++i){ a[i]^=0x80008000u; b[i]^=0x80008000u; }
  }
  Frag f; f.h = __builtin_bit_cast(half8, a); f.l = __builtin_bit_cast(half8, b);
  return f;
}

static __device__ __forceinline__ Frag ldbg(const u32* FL, int grp, int lane){
  const u32* p = FL + ((size_t)(grp*64 + lane))*8;
  u32x4 a = *reinterpret_cast<const u32x4*>(p);
  u32x4 b = *reinterpret_cast<const u32x4*>(p+4);
  Frag f; f.h = __builtin_bit_cast(half8, a); f.l = __builtin_bit_cast(half8, b);
  return f;
}

static __device__ __forceinline__ void store_tile(u32* O, int ti, int tj, int h, int c15,
                                                  const float* x){
  const int s = h & 1;
  const int lp = c15 + 16*((2*ti + (h>>1)) & 3);
  const int g = GIDX(tj, ti>>1, lp);
  u32x2 hw, lw; split4(x, hw, lw);
  *reinterpret_cast<u32x2*>(O + g*4 + 2*s) = hw;
  *reinterpret_cast<u32x2*>(O + 2048 + g*4 + 2*s) = lw;
}

static __device__ __forceinline__ void read_tile(const u32* O, int ti, int tj, int h, int c15,
                                                 float* n){
  const int s = h & 1;
  const int lp = c15 + 16*((2*ti + (h>>1)) & 3);
  const int g = GIDX(tj, ti>>1, lp);
  u32x2 nh = *reinterpret_cast<const u32x2*>(O + g*4 + 2*s);
  u32x2 nl = *reinterpret_cast<const u32x2*>(O + 2048 + g*4 + 2*s);
  up2v(nh[0],nl[0],n[0],n[1]); up2v(nh[1],nl[1],n[2],n[3]);
}

// ---------------- Kernel A: projections + s + u = Ux @ s -------------------
__global__ __launch_bounds__(64) void proj_kernel(
    const float* __restrict__ x, const float* __restrict__ amp_w,
    const float* __restrict__ amp_b, const float* __restrict__ phase_w,
    const float* __restrict__ phase_b, const float* __restrict__ Ux,
    float* __restrict__ u_out) {
    __shared__ float xr[INDIM];
    __shared__ float s_r[D_], s_i[D_];
    const int bt = blockIdx.x;
    const int b = bt / T_, t = bt % T_;
    const float* xrow = x + (size_t)bt * INDIM;
    for (int i = threadIdx.x; i < INDIM; i += 64) xr[i] = xrow[i];
    __syncthreads();
    const int d = threadIdx.x;
    float a = amp_b[d], p = phase_b[d];
    for (int k = 0; k < INDIM; ++k) {
        float xv = xr[k];
        a = fmaf(xv, amp_w[k * D_ + d], a);
        p = fmaf(xv, phase_w[k * D_ + d], p);
    }
    float sq = a * a;
    #pragma unroll
    for (int off = 32; off > 0; off >>= 1) sq += __shfl_xor(sq, off);
    float an = a / sqrtf(sq);
    s_r[d] = an * cosf(p);
    s_i[d] = an * sinf(p);
    __syncthreads();
    float ur = 0.f, ui = 0.f;
    const float* Uxrow = Ux + d * D_;
    for (int e = 0; e < D_; ++e) {
        float uv = Uxrow[e];
        ur = fmaf(uv, s_r[e], ur);
        ui = fmaf(uv, s_i[e], ui);
    }
    float* ub = u_out + ((size_t)t * B_ + b) * 128;
    ub[d] = ur;
    ub[64 + d] = ui;
}

// ---------------- Kernel B: operand-fragment precompute --------------------
__global__ __launch_bounds__(256) void setup_kernel(
    const float* __restrict__ Uh, const float* __restrict__ Ux,
    const float* __restrict__ W, const float* __restrict__ meas,
    u32* __restrict__ UhFL, u32* __restrict__ UxFL,
    u32* __restrict__ AB2FL, float* __restrict__ AB2p, float* __restrict__ ABt)
{
  const int tid = threadIdx.x;
  for (int wi = tid; wi < 4096; wi += 256){
    int off = wi & 7, g = wi >> 3;
    int lane_ = g & 63, cbkc = g >> 6;
    int cb = cbkc >> 1, kc = cbkc & 1;
    int wq = off & 3; bool isHi = off < 4;
    int k0 = 32*kc + 8*(lane_>>4) + 2*wq;
    int c  = 16*cb + (lane_&15);
    {
      float x0 = Uh[c*64 + k0], x1 = Uh[c*64 + k0 + 1];
      _Float16 h0=(_Float16)x0, h1=(_Float16)x1;
      UhFL[wi] = isHi ? pkh(h0,h1)
                      : pkh((_Float16)(x0-(float)h0), (_Float16)(x1-(float)h1));
    }
    {
      float x0 = Ux[c*64 + k0], x1 = Ux[c*64 + k0 + 1];
      _Float16 h0=(_Float16)x0, h1=(_Float16)x1;
      UxFL[wi] = isHi ? pkh(h0,h1)
                      : pkh((_Float16)(x0-(float)h0), (_Float16)(x1-(float)h1));
    }
  }
  __shared__ float invn[C_];
  if (tid < C_) {
    float s = 0.f;
    for (int j = 0; j < C_; ++j) {
      float vr = meas[(tid * C_ + j) * 2], vi = meas[(tid * C_ + j) * 2 + 1];
      s += vr * vr + vi * vi;
    }
    invn[tid] = 1.0f / sqrtf(s);
  }
  __syncthreads();
  for (int i = tid; i < D_ * 32; i += 256) {
    int dd = i >> 5, c = i & 31;
    float v = 0.f;
    if (c < C_) {
      float acc = 0.f;
      for (int j = 0; j < C_; ++j) acc = fmaf(W[dd * C_ + j], meas[(c * C_ + j) * 2], acc);
      v = acc * invn[c];
    } else if (c < 2 * C_) {
      int k = c - C_;
      float acc = 0.f;
      for (int j = 0; j < C_; ++j) acc = fmaf(W[dd * C_ + j], meas[(k * C_ + j) * 2 + 1], acc);
      v = acc * invn[k];
    } else if (c < 3 * C_) {
      v = W[dd * C_ + (c - 2 * C_)];
    }
    AB2p[i] = v;
  }
  __syncthreads();
  // AB2FL fragment layout
  for (int wi = tid; wi < 2048; wi += 256){
    int off = wi & 7, g = wi >> 3;
    int lane_ = g & 63, cbkc = g >> 6;
    int cb = cbkc >> 1, kc = cbkc & 1;
    int wq = off & 3; bool isHi = off < 4;
    int k0 = 32*kc + 8*(lane_>>4) + 2*wq;
    int c  = 16*cb + (lane_&15);
    float x0 = AB2p[k0*32 + c], x1 = AB2p[(k0+1)*32 + c];
    _Float16 h0=(_Float16)x0, h1=(_Float16)x1;
    AB2FL[wi] = isHi ? pkh(h0,h1)
                     : pkh((_Float16)(x0-(float)h0), (_Float16)(x1-(float)h1));
  }
  // ABt[c][d] = AB2p[d][c], c<30 (coalesced meas reads)
  for (int i = tid; i < 30*64; i += 256){
    int c = i >> 6, d = i & 63;
    ABt[i] = AB2p[d*32 + c];
  }
}

// ---------------- Kernel C: fused 2-layer scan + dense + measurement -------
__global__ __launch_bounds__(1024, 4) void qrnn_kernel(
    const float* __restrict__ u_in,
    const u32* __restrict__ UhFL, const u32* __restrict__ UxFL,
    const u32* __restrict__ AB2FL, const float* __restrict__ ABt,
    const float* __restrict__ cell_lambda, const float* __restrict__ dense_lambda,
    float* __restrict__ out)
{
  // 9 matrix buffers, each 4096 u32 (hi 2048 | lo 2048)
  __shared__ __align__(16) u32 ds[9*4096];
  __shared__ float u_lds[128];
  __shared__ float scrN1[16], scrNp[16], scrQ[12];

  const int tid = threadIdx.x;
  const int lane = tid & 63;
  const int w = tid >> 6;          // 0..15
  const int h = lane >> 4;
  const int c15 = lane & 15;
  const int bidx = blockIdx.x;
  const float lam = sigmoidf_(cell_lambda[0]);
  const float clm = 1.f - lam;
  const float dlam = sigmoidf_(dense_lambda[0]);

  u32* const B0 = ds + 0*4096;   // h1R
  u32* const B1 = ds + 1*4096;   // h1I
  u32* const B2 = ds + 2*4096;   // h2R (fixed)
  u32* const B3 = ds + 3*4096;
  u32* const B4 = ds + 4*4096;
  u32* const B5 = ds + 5*4096;   // T1I / TXI
  u32* const B6 = ds + 6*4096;   // Zt (fp32 30x129) / THR
  u32* const B7 = ds + 7*4096;   // N1R / THI
  u32* const B8 = ds + 8*4096;   // N1I / N'R
  float* const Zt = reinterpret_cast<float*>(B6);

  // ---- init h1 = h2 = I/64 ----
  const u32 one64 = (u32)__builtin_bit_cast(unsigned short, (_Float16)0.015625f);
  for (int wi = tid; wi < 4096; wi += 1024){
    u32 vR = 0u;
    if (wi < 2048){
      int g = wi >> 2, wq = wi & 3;
      int lane_ = g & 63, cbkc = g >> 6;
      int cb = cbkc >> 1, kc = cbkc & 1;
      int k0 = 32*kc + 8*(lane_>>4) + 2*wq;
      int c = 16*cb + (lane_&15);
      if (k0 == c)   vR |= one64;
      if (k0+1 == c) vR |= (one64 << 16);
    }
    B0[wi] = vR; B2[wi] = vR; B1[wi] = 0u; B3[wi] = 0u;
  }
  __syncthreads();

  for (int t = 0; t <= T_; ++t){
    const bool doMain = (t < T_);
    const bool doTail = (t > 0);
    const int par = t & 1;
    u32* const pH2I = par ? B4 : B3;   // h2I in-state; also N' I dest
    u32* const pTXR = par ? B3 : B4;   // T1R/TXR dest; also h2I out-state

    // ================= Phase 1: T1 = GEMM(h1,Uh)  +  dense(t-1) ===========
    if (doMain){
      if (tid < 128) u_lds[tid] = u_in[((size_t)t*B_ + bidx)*128 + tid];
      const int comp = w>>3, ti=(w>>1)&3, tjh=w&1;
      const u32* A = comp ? B1 : B0;
      Frag a0 = ldfrag(A, GIDX(ti,0,lane), false);
      Frag a1 = ldfrag(A, GIDX(ti,1,lane), false);
      u32* O = comp ? B5 : pTXR;
#pragma unroll
      for (int jj=0;jj<2;++jj){
        const int tj = 2*tjh + jj;
        Frag b0 = ldbg(UhFL, tj*2+0, lane);
        Frag b1 = ldbg(UhFL, tj*2+1, lane);
        f32x4 acc = {0.f,0.f,0.f,0.f};
        mfma4(a0,b0,acc); mfma4(a1,b1,acc);
        float xv[4] = {acc[0],acc[1],acc[2],acc[3]};
        store_tile(O, ti, tj, h, c15, xv);
      }
    }
    if (doTail){
      const int rb = w>>1, cz = w&1, cb = rb&3;
      const u32* A = (rb<4) ? B2 : pH2I;
      Frag a0 = ldfrag(A, GIDX(cb,0,lane), false);
      Frag a1 = ldfrag(A, GIDX(cb,1,lane), false);
      Frag b0 = ldbg(AB2FL, cz*2+0, lane);
      Frag b1 = ldbg(AB2FL, cz*2+1, lane);
      f32x4 za = {0.f,0.f,0.f,0.f};
      mfma4(a0,b0,za); mfma4(a1,b1,za);
      const int c = 16*cz + c15;
      if (c < 30){
        float* zp = Zt + c*129 + 16*rb + 4*h;
#pragma unroll
        for (int rr=0;rr<4;++rr) zp[rr] = za[rr];
      }
    }
    __syncthreads();

    // ===== Phase 2: N1 = lam*outer(u) + (1-lam)*GEMM(T1,Uh); sumsq  + meas =
    if (doMain){
      const int comp = w>>3, ti=(w>>1)&3, tjh=w&1;
      const u32* A = comp ? B5 : pTXR;
      Frag a0 = ldfrag(A, GIDX(ti,0,lane), false);
      Frag a1 = ldfrag(A, GIDX(ti,1,lane), false);
      u32* O = comp ? B8 : B7;
      float uR[4], uI[4];
#pragma unroll
      for (int rr=0;rr<4;++rr){
        uR[rr] = u_lds[16*ti + 4*h + rr];
        uI[rr] = u_lds[64 + 16*ti + 4*h + rr];
      }
      float ss = 0.f;
#pragma unroll
      for (int jj=0;jj<2;++jj){
        const int tj = 2*tjh + jj;
        Frag b0 = ldbg(UhFL, tj*2+0, lane);
        Frag b1 = ldbg(UhFL, tj*2+1, lane);
        f32x4 acc = {0.f,0.f,0.f,0.f};
        mfma4(a0,b0,acc); mfma4(a1,b1,acc);
        const float urc = u_lds[16*tj + c15], uic = u_lds[64 + 16*tj + c15];
        float xv[4];
#pragma unroll
        for (int rr=0;rr<4;++rr){
          float ov = comp ? (uI[rr]*urc - uR[rr]*uic) : (uR[rr]*urc + uI[rr]*uic);
          xv[rr] = lam*ov + clm*acc[rr];
          ss = fmaf(xv[rr], xv[rr], ss);
        }
        store_tile(O, ti, tj, h, c15, xv);
      }
      ss = wave_sum(ss);
      if (lane == 0) scrN1[w] = ss;
    }
    if (doTail && w < 11){
      if (w < 10){
        float av = ABt[w*64 + lane], bv = ABt[(10+w)*64 + lane];
        float z1a = Zt[w*129 + lane],      z1b = Zt[(10+w)*129 + lane];
        float z2a = Zt[w*129 + 64 + lane], z2b = Zt[(10+w)*129 + 64 + lane];
        float v = av*z1a + bv*z1b + av*z2b - bv*z2a;
        v = wave_sum(v);
        if (lane == 0) scrQ[w] = v;
      } else {
        float v = 0.f;
#pragma unroll
        for (int cc=0; cc<10; ++cc)
          v = fmaf(ABt[(20+cc)*64 + lane], Zt[(20+cc)*129 + lane], v);
        v = wave_sum(v);
        if (lane == 0) scrQ[10] = v;
      }
    }
    __syncthreads();

    // ================= Phase 3: h1 = act(N1)  +  out(t-1) ==================
    if (doMain){
      const int o = w>>3, p = w&7, tj = p&3, t0 = p>>2;   // ti in {t0, t0+2}
      f32x4 acc[2];
      acc[0] = f32x4{0.f,0.f,0.f,0.f}; acc[1] = f32x4{0.f,0.f,0.f,0.f};
#pragma unroll
      for (int m=0;m<2;++m){
        const u32* Ab = m ? B8 : B7;
        const u32* Bb = o ? (m ? B7 : B8) : (m ? B8 : B7);
        const bool neg = (o==1) && (m==1);
#pragma unroll
        for (int kc=0;kc<2;++kc){
          Frag bf  = ldfrag(Bb, GIDX(tj,kc,lane), false);
          Frag af0 = ldfrag(Ab, GIDX(t0,kc,lane), neg);
          Frag af1 = ldfrag(Ab, GIDX(t0+2,kc,lane), neg);
          mfma4(af0, bf, acc[0]);
          mfma4(af1, bf, acc[1]);
        }
      }
      const f32x4* sv = reinterpret_cast<const f32x4*>(scrN1);
      f32x4 s4 = sv[0] + sv[1] + sv[2] + sv[3];
      const float trv = s4[0]+s4[1]+s4[2]+s4[3];
      const float sb = BETA_/trv, cbm = 1.f - BETA_;
      const u32* Nsrc = o ? B8 : B7;
      u32* Od = o ? B1 : B0;
#pragma unroll
      for (int it=0; it<2; ++it){
        const int ti = t0 + 2*it;
        float n[4]; read_tile(Nsrc, ti, tj, h, c15, n);
        float xv[4];
#pragma unroll
        for (int rr=0;rr<4;++rr) xv[rr] = fmaf(sb, acc[it][rr], cbm*n[rr]);
        store_tile(Od, ti, tj, h, c15, xv);
      }
    }
    if (doTail && tid < 10){
      float pnum = dlam*scrQ[tid] + (1.f-dlam)*0.1f;
      float pden = dlam*scrQ[10] + (1.f-dlam);
      out[((size_t)bidx*T_ + (t-1))*C_ + tid] = logf(pnum/pden);
    }
    __syncthreads();

    if (doMain){
      // ============ Phase 4: TX = GEMM(h1,Ux), TH = GEMM(h2,Uh) ============
      {
        const int g2 = w>>3, comp=(w>>2)&1, ti=w&3;
        const u32* A = g2 ? (comp? pH2I : B2) : (comp? B1 : B0);
        const u32* FL = g2 ? UhFL : UxFL;
        u32* O = g2 ? (comp? B7 : B6) : (comp? B5 : pTXR);
        Frag a0 = ldfrag(A, GIDX(ti,0,lane), false);
        Frag a1 = ldfrag(A, GIDX(ti,1,lane), false);
#pragma unroll
        for (int tj=0;tj<4;++tj){
          Frag b0 = ldbg(FL, tj*2+0, lane);
          Frag b1 = ldbg(FL, tj*2+1, lane);
          f32x4 acc = {0.f,0.f,0.f,0.f};
          mfma4(a0,b0,acc); mfma4(a1,b1,acc);
          float xv[4] = {acc[0],acc[1],acc[2],acc[3]};
          store_tile(O, ti, tj, h, c15, xv);
        }
      }
      __syncthreads();

      // ====== Phase 5: N' = lam*GEMM(TX,Ux) + (1-lam)*GEMM(TH,Uh); sumsq ===
      {
        const int comp = w>>3, ti=(w>>1)&3, tjh=w&1;
        const u32* AX = comp ? B5 : pTXR;
        const u32* AH = comp ? B7 : B6;
        Frag ax0 = ldfrag(AX, GIDX(ti,0,lane), false);
        Frag ax1 = ldfrag(AX, GIDX(ti,1,lane), false);
        Frag ah0 = ldfrag(AH, GIDX(ti,0,lane), false);
        Frag ah1 = ldfrag(AH, GIDX(ti,1,lane), false);
        u32* O = comp ? pH2I : B8;
        float ss = 0.f;
#pragma unroll
        for (int jj=0;jj<2;++jj){
          const int tj = 2*tjh + jj;
          Frag bx0 = ldbg(UxFL, tj*2+0, lane);
          Frag bx1 = ldbg(UxFL, tj*2+1, lane);
          f32x4 aX = {0.f,0.f,0.f,0.f};
          mfma4(ax0,bx0,aX); mfma4(ax1,bx1,aX);
          Frag bh0 = ldbg(UhFL, tj*2+0, lane);
          Frag bh1 = ldbg(UhFL, tj*2+1, lane);
          f32x4 aH = {0.f,0.f,0.f,0.f};
          mfma4(ah0,bh0,aH); mfma4(ah1,bh1,aH);
          float xv[4];
#pragma unroll
          for (int rr=0;rr<4;++rr){
            xv[rr] = lam*aX[rr] + clm*aH[rr];
            ss = fmaf(xv[rr], xv[rr], ss);
          }
          store_tile(O, ti, tj, h, c15, xv);
        }
        ss = wave_sum(ss);
        if (lane == 0) scrNp[w] = ss;
      }
      __syncthreads();

      // ================= Phase 6: h2 = act(N') ==============================
      {
        const int o = w>>3, p = w&7, tj = p&3, t0 = p>>2;
        const u32* NPR = B8;
        const u32* NPI = pH2I;
        f32x4 acc[2];
        acc[0] = f32x4{0.f,0.f,0.f,0.f}; acc[1] = f32x4{0.f,0.f,0.f,0.f};
#pragma unroll
        for (int m=0;m<2;++m){
          const u32* Ab = m ? NPI : NPR;
          const u32* Bb = o ? (m ? NPR : NPI) : (m ? NPI : NPR);
          const bool neg = (o==1) && (m==1);
#pragma unroll
          for (int kc=0;kc<2;++kc){
            Frag bf  = ldfrag(Bb, GIDX(tj,kc,lane), false);
            Frag af0 = ldfrag(Ab, GIDX(t0,kc,lane), neg);
            Frag af1 = ldfrag(Ab, GIDX(t0+2,kc,lane), neg);
            mfma4(af0, bf, acc[0]);
            mfma4(af1, bf, acc[1]);
          }
        }
        const f32x4* sv = reinterpret_cast<const f32x4*>(scrNp);
        f32x4 s4 = sv[0] + sv[1] + sv[2] + sv[3];
        const float trv = s4[0]+s4[1]+s4[2]+s4[3];
        const float sb = BETA_/trv, cbm = 1.f - BETA_;
        const u32* Nsrc = o ? NPI : NPR;
        u32* Od = o ? pTXR : B2;    // h2 out: (B2, pTXR)
#pragma unroll
        for (int it=0; it<2; ++it){
          const int ti = t0 + 2*it;
          float n[4]; read_tile(Nsrc, ti, tj, h, c15, n);
          float xv[4];
#pragma unroll
          for (int rr=0;rr<4;++rr) xv[rr] = fmaf(sb, acc[it][rr], cbm*n[rr]);
          store_tile(Od, ti, tj, h, c15, xv);
        }
      }
      __syncthreads();
    }
  }
}

extern "C" void kernel_launch(void* const* d_in, const int* in_sizes, int n_in,
                              void* d_out, int out_size, void* d_ws, size_t ws_size,
                              hipStream_t stream) {
    const float* x       = (const float*)d_in[0];
    const float* amp_w   = (const float*)d_in[1];
    const float* amp_b   = (const float*)d_in[2];
    const float* phase_w = (const float*)d_in[3];
    const float* phase_b = (const float*)d_in[4];
    const float* Ux      = (const float*)d_in[5];
    const float* Uh      = (const float*)d_in[6];
    const float* cl      = (const float*)d_in[7];
    const float* W       = (const float*)d_in[8];
    const float* dl      = (const float*)d_in[9];
    const float* meas    = (const float*)d_in[10];

    float* ws   = (float*)d_ws;
    float* u    = ws;                                  // 128*64*128 f32
    u32*  UhFL  = (u32*)(ws + 1048576);                // 4096
    u32*  UxFL  = UhFL + 4096;                         // 4096
    u32*  AB2FL = UxFL + 4096;                         // 2048
    float* AB2p = (float*)(AB2FL + 2048);              // 2048
    float* ABt  = AB2p + 2048;                         // 1920
    float* out  = (float*)d_out;

    proj_kernel<<<B_ * T_, 64, 0, stream>>>(x, amp_w, amp_b, phase_w, phase_b, Ux, u);
    setup_kernel<<<1, 256, 0, stream>>>(Uh, Ux, W, meas, UhFL, UxFL, AB2FL, AB2p, ABt);
    qrnn_kernel<<<B_, 1024, 0, stream>>>(u, UhFL, UxFL, AB2FL, ABt, cl, dl, out);
}

// Round 4
// 2040.966 us; speedup vs baseline: 1.0581x; 1.0581x over previous
//
#include <hip/hip_runtime.h>
#include <math.h>

#define B_ 64
#define T_ 128
#define INDIM 300
#define D_ 64
#define C_ 10
#define BETA_ 0.8f

typedef unsigned int u32;
typedef _Float16 half8 __attribute__((ext_vector_type(8)));
typedef float f32x4 __attribute__((ext_vector_type(4)));
typedef u32 u32x4 __attribute__((ext_vector_type(4)));
typedef u32 u32x2 __attribute__((ext_vector_type(2)));

// fragment-group index: cb = 16-col block, kc = 32-k block
#define GIDX(cb,kc,ln) ((((cb)*2+(kc))*64) + (ln))

struct Frag { half8 h, l; };

static __device__ __forceinline__ float sigmoidf_(float x){ return 1.f/(1.f+expf(-x)); }

static __device__ __forceinline__ float wave_sum(float v){
#pragma unroll
  for (int off = 32; off > 0; off >>= 1) v += __shfl_down(v, off);
  return v;
}

static __device__ __forceinline__ u32 pkh(_Float16 a, _Float16 b){
  unsigned short ba = __builtin_bit_cast(unsigned short, a);
  unsigned short bb = __builtin_bit_cast(unsigned short, b);
  return (u32)ba | ((u32)bb << 16);
}

static __device__ __forceinline__ void split4(const float* x, u32x2& hw, u32x2& lw){
  _Float16 h0=(_Float16)x[0], h1=(_Float16)x[1], h2=(_Float16)x[2], h3=(_Float16)x[3];
  _Float16 l0=(_Float16)(x[0]-(float)h0), l1=(_Float16)(x[1]-(float)h1);
  _Float16 l2=(_Float16)(x[2]-(float)h2), l3=(_Float16)(x[3]-(float)h3);
  hw[0]=pkh(h0,h1); hw[1]=pkh(h2,h3); lw[0]=pkh(l0,l1); lw[1]=pkh(l2,l3);
}

static __device__ __forceinline__ void up2v(u32 hw, u32 lw, float& v0, float& v1){
  _Float16 h0=__builtin_bit_cast(_Float16,(unsigned short)(hw & 0xffffu));
  _Float16 h1=__builtin_bit_cast(_Float16,(unsigned short)(hw >> 16));
  _Float16 l0=__builtin_bit_cast(_Float16,(unsigned short)(lw & 0xffffu));
  _Float16 l1=__builtin_bit_cast(_Float16,(unsigned short)(lw >> 16));
  v0 = (float)h0 + (float)l0;
  v1 = (float)h1 + (float)l1;
}

static __device__ __forceinline__ void mfma4(const Frag& a, const Frag& b, f32x4& acc){
  acc = __builtin_amdgcn_mfma_f32_16x16x32_f16(a.h, b.h, acc, 0, 0, 0);
  acc = __builtin_amdgcn_mfma_f32_16x16x32_f16(a.h, b.l, acc, 0, 0, 0);
  acc = __builtin_amdgcn_mfma_f32_16x16x32_f16(a.l, b.h, acc, 0, 0, 0);
  acc = __builtin_amdgcn_mfma_f32_16x16x32_f16(a.l, b.l, acc, 0, 0, 0);
}

static __device__ __forceinline__ Frag ldfrag(const u32* buf, int g, bool neg){
  u32x4 a = *reinterpret_cast<const u32x4*>(buf + g*4);
  u32x4 b = *reinterpret_cast<const u32x4*>(buf + 2048 + g*4);
  if (neg){
#pragma unroll
    for (int i=0;i<4;++i){ a[i]^=0x80008000u; b[i]^=0x80008000u; }
  }
  Frag f; f.h = __builtin_bit_cast(half8, a); f.l = __builtin_bit_cast(half8, b);
  return f;
}

static __device__ __forceinline__ Frag ldbg(const u32* FL, int grp, int lane){
  const u32* p = FL + ((size_t)(grp*64 + lane))*8;
  u32x4 a = *reinterpret_cast<const u32x4*>(p);
  u32x4 b = *reinterpret_cast<const u32x4*>(p+4);
  Frag f; f.h = __builtin_bit_cast(half8, a); f.l = __builtin_bit_cast(half8, b);
  return f;
}

static __device__ __forceinline__ void store_tile(u32* O, int ti, int tj, int h, int c15,
                                                  const float* x){
  const int s = h & 1;
  const int lp = c15 + 16*((2*ti + (h>>1)) & 3);
  const int g = GIDX(tj, ti>>1, lp);
  u32x2 hw, lw; split4(x, hw, lw);
  *reinterpret_cast<u32x2*>(O + g*4 + 2*s) = hw;
  *reinterpret_cast<u32x2*>(O + 2048 + g*4 + 2*s) = lw;
}

static __device__ __forceinline__ void read_tile(const u32* O, int ti, int tj, int h, int c15,
                                                 float* n){
  const int s = h & 1;
  const int lp = c15 + 16*((2*ti + (h>>1)) & 3);
  const int g = GIDX(tj, ti>>1, lp);
  u32x2 nh = *reinterpret_cast<const u32x2*>(O + g*4 + 2*s);
  u32x2 nl = *reinterpret_cast<const u32x2*>(O + 2048 + g*4 + 2*s);
  up2v(nh[0],nl[0],n[0],n[1]); up2v(nh[1],nl[1],n[2],n[3]);
}

// ---------------- Kernel A: projections + s + u = Ux @ s -------------------
__global__ __launch_bounds__(64) void proj_kernel(
    const float* __restrict__ x, const float* __restrict__ amp_w,
    const float* __restrict__ amp_b, const float* __restrict__ phase_w,
    const float* __restrict__ phase_b, const float* __restrict__ Ux,
    float* __restrict__ u_out) {
    __shared__ float xr[INDIM];
    __shared__ float s_r[D_], s_i[D_];
    const int bt = blockIdx.x;
    const int b = bt / T_, t = bt % T_;
    const float* xrow = x + (size_t)bt * INDIM;
    for (int i = threadIdx.x; i < INDIM; i += 64) xr[i] = xrow[i];
    __syncthreads();
    const int d = threadIdx.x;
    float a = amp_b[d], p = phase_b[d];
    for (int k = 0; k < INDIM; ++k) {
        float xv = xr[k];
        a = fmaf(xv, amp_w[k * D_ + d], a);
        p = fmaf(xv, phase_w[k * D_ + d], p);
    }
    float sq = a * a;
    #pragma unroll
    for (int off = 32; off > 0; off >>= 1) sq += __shfl_xor(sq, off);
    float an = a / sqrtf(sq);
    s_r[d] = an * cosf(p);
    s_i[d] = an * sinf(p);
    __syncthreads();
    float ur = 0.f, ui = 0.f;
    const float* Uxrow = Ux + d * D_;
    for (int e = 0; e < D_; ++e) {
        float uv = Uxrow[e];
        ur = fmaf(uv, s_r[e], ur);
        ui = fmaf(uv, s_i[e], ui);
    }
    float* ub = u_out + ((size_t)t * B_ + b) * 128;
    ub[d] = ur;
    ub[64 + d] = ui;
}

// ---------------- Kernel B: operand-fragment precompute --------------------
__global__ __launch_bounds__(256) void setup_kernel(
    const float* __restrict__ Uh, const float* __restrict__ Ux,
    const float* __restrict__ W, const float* __restrict__ meas,
    u32* __restrict__ UhFL, u32* __restrict__ UxFL,
    u32* __restrict__ AB2FL, float* __restrict__ AB2p, float* __restrict__ ABt)
{
  const int tid = threadIdx.x;
  for (int wi = tid; wi < 4096; wi += 256){
    int off = wi & 7, g = wi >> 3;
    int lane_ = g & 63, cbkc = g >> 6;
    int cb = cbkc >> 1, kc = cbkc & 1;
    int wq = off & 3; bool isHi = off < 4;
    int k0 = 32*kc + 8*(lane_>>4) + 2*wq;
    int c  = 16*cb + (lane_&15);
    {
      float x0 = Uh[c*64 + k0], x1 = Uh[c*64 + k0 + 1];
      _Float16 h0=(_Float16)x0, h1=(_Float16)x1;
      UhFL[wi] = isHi ? pkh(h0,h1)
                      : pkh((_Float16)(x0-(float)h0), (_Float16)(x1-(float)h1));
    }
    {
      float x0 = Ux[c*64 + k0], x1 = Ux[c*64 + k0 + 1];
      _Float16 h0=(_Float16)x0, h1=(_Float16)x1;
      UxFL[wi] = isHi ? pkh(h0,h1)
                      : pkh((_Float16)(x0-(float)h0), (_Float16)(x1-(float)h1));
    }
  }
  __shared__ float invn[C_];
  if (tid < C_) {
    float s = 0.f;
    for (int j = 0; j < C_; ++j) {
      float vr = meas[(tid * C_ + j) * 2], vi = meas[(tid * C_ + j) * 2 + 1];
      s += vr * vr + vi * vi;
    }
    invn[tid] = 1.0f / sqrtf(s);
  }
  __syncthreads();
  for (int i = tid; i < D_ * 32; i += 256) {
    int dd = i >> 5, c = i & 31;
    float v = 0.f;
    if (c < C_) {
      float acc = 0.f;
      for (int j = 0; j < C_; ++j) acc = fmaf(W[dd * C_ + j], meas[(c * C_ + j) * 2], acc);
      v = acc * invn[c];
    } else if (c < 2 * C_) {
      int k = c - C_;
      float acc = 0.f;
      for (int j = 0; j < C_; ++j) acc = fmaf(W[dd * C_ + j], meas[(k * C_ + j) * 2 + 1], acc);
      v = acc * invn[k];
    } else if (c < 3 * C_) {
      v = W[dd * C_ + (c - 2 * C_)];
    }
    AB2p[i] = v;
  }
  __syncthreads();
  // AB2FL fragment layout
  for (int wi = tid; wi < 2048; wi += 256){
    int off = wi & 7, g = wi >> 3;
    int lane_ = g & 63, cbkc = g >> 6;
    int cb = cbkc >> 1, kc = cbkc & 1;
    int wq = off & 3; bool isHi = off < 4;
    int k0 = 32*kc + 8*(lane_>>4) + 2*wq;
    int c  = 16*cb + (lane_&15);
    float x0 = AB2p[k0*32 + c], x1 = AB2p[(k0+1)*32 + c];
    _Float16 h0=(_Float16)x0, h1=(_Float16)x1;
    AB2FL[wi] = isHi ? pkh(h0,h1)
                     : pkh((_Float16)(x0-(float)h0), (_Float16)(x1-(float)h1));
  }
  // ABt[c][d] = AB2p[d][c], c<30 (coalesced meas reads)
  for (int i = tid; i < 30*64; i += 256){
    int c = i >> 6, d = i & 63;
    ABt[i] = AB2p[d*32 + c];
  }
}

// ---------------- Kernel C: fused 2-layer scan + dense + measurement -------
// launch_bounds(1024, 1): 1 block/CU -> 16 waves/CU (4/SIMD) -> VGPR cap 128.
// (1024,4) in the previous round meant 4 BLOCKS/CU (CUDA semantics) -> VGPR
// capped at 64 -> massive scratch spills (WRITE_SIZE 17.5 MB). Do not repeat.
__global__ __launch_bounds__(1024, 1) void qrnn_kernel(
    const float* __restrict__ u_in,
    const u32* __restrict__ UhFL, const u32* __restrict__ UxFL,
    const u32* __restrict__ AB2FL, const float* __restrict__ ABt,
    const float* __restrict__ cell_lambda, const float* __restrict__ dense_lambda,
    float* __restrict__ out)
{
  // 9 matrix buffers, each 4096 u32 (hi 2048 | lo 2048)
  __shared__ __align__(16) u32 ds[9*4096];
  __shared__ float u_lds[128];
  __shared__ float scrN1[16], scrNp[16], scrQ[12];

  const int tid = threadIdx.x;
  const int lane = tid & 63;
  const int w = tid >> 6;          // 0..15
  const int h = lane >> 4;
  const int c15 = lane & 15;
  const int bidx = blockIdx.x;
  const float lam = sigmoidf_(cell_lambda[0]);
  const float clm = 1.f - lam;
  const float dlam = sigmoidf_(dense_lambda[0]);

  u32* const B0 = ds + 0*4096;   // h1R
  u32* const B1 = ds + 1*4096;   // h1I
  u32* const B2 = ds + 2*4096;   // h2R (fixed)
  u32* const B3 = ds + 3*4096;
  u32* const B4 = ds + 4*4096;
  u32* const B5 = ds + 5*4096;   // T1I / TXI
  u32* const B6 = ds + 6*4096;   // Zt (fp32 30x129) / THR
  u32* const B7 = ds + 7*4096;   // N1R / THI
  u32* const B8 = ds + 8*4096;   // N1I / N'R
  float* const Zt = reinterpret_cast<float*>(B6);

  // ---- init h1 = h2 = I/64 ----
  const u32 one64 = (u32)__builtin_bit_cast(unsigned short, (_Float16)0.015625f);
  for (int wi = tid; wi < 4096; wi += 1024){
    u32 vR = 0u;
    if (wi < 2048){
      int g = wi >> 2, wq = wi & 3;
      int lane_ = g & 63, cbkc = g >> 6;
      int cb = cbkc >> 1, kc = cbkc & 1;
      int k0 = 32*kc + 8*(lane_>>4) + 2*wq;
      int c = 16*cb + (lane_&15);
      if (k0 == c)   vR |= one64;
      if (k0+1 == c) vR |= (one64 << 16);
    }
    B0[wi] = vR; B2[wi] = vR; B1[wi] = 0u; B3[wi] = 0u;
  }
  __syncthreads();

  for (int t = 0; t <= T_; ++t){
    const bool doMain = (t < T_);
    const bool doTail = (t > 0);
    const int par = t & 1;
    u32* const pH2I = par ? B4 : B3;   // h2I in-state; also N' I dest
    u32* const pTXR = par ? B3 : B4;   // T1R/TXR dest; also h2I out-state

    // ================= Phase 1: T1 = GEMM(h1,Uh)  +  dense(t-1) ===========
    if (doMain){
      if (tid < 128) u_lds[tid] = u_in[((size_t)t*B_ + bidx)*128 + tid];
      const int comp = w>>3, ti=(w>>1)&3, tjh=w&1;
      const u32* A = comp ? B1 : B0;
      Frag a0 = ldfrag(A, GIDX(ti,0,lane), false);
      Frag a1 = ldfrag(A, GIDX(ti,1,lane), false);
      u32* O = comp ? B5 : pTXR;
#pragma unroll
      for (int jj=0;jj<2;++jj){
        const int tj = 2*tjh + jj;
        Frag b0 = ldbg(UhFL, tj*2+0, lane);
        Frag b1 = ldbg(UhFL, tj*2+1, lane);
        f32x4 acc = {0.f,0.f,0.f,0.f};
        mfma4(a0,b0,acc); mfma4(a1,b1,acc);
        float xv[4] = {acc[0],acc[1],acc[2],acc[3]};
        store_tile(O, ti, tj, h, c15, xv);
      }
    }
    if (doTail){
      const int rb = w>>1, cz = w&1, cb = rb&3;
      const u32* A = (rb<4) ? B2 : pH2I;
      Frag a0 = ldfrag(A, GIDX(cb,0,lane), false);
      Frag a1 = ldfrag(A, GIDX(cb,1,lane), false);
      Frag b0 = ldbg(AB2FL, cz*2+0, lane);
      Frag b1 = ldbg(AB2FL, cz*2+1, lane);
      f32x4 za = {0.f,0.f,0.f,0.f};
      mfma4(a0,b0,za); mfma4(a1,b1,za);
      const int c = 16*cz + c15;
      if (c < 30){
        float* zp = Zt + c*129 + 16*rb + 4*h;
#pragma unroll
        for (int rr=0;rr<4;++rr) zp[rr] = za[rr];
      }
    }
    __syncthreads();

    // ===== Phase 2: N1 = lam*outer(u) + (1-lam)*GEMM(T1,Uh); sumsq  + meas =
    if (doMain){
      const int comp = w>>3, ti=(w>>1)&3, tjh=w&1;
      const u32* A = comp ? B5 : pTXR;
      Frag a0 = ldfrag(A, GIDX(ti,0,lane), false);
      Frag a1 = ldfrag(A, GIDX(ti,1,lane), false);
      u32* O = comp ? B8 : B7;
      float uR[4], uI[4];
#pragma unroll
      for (int rr=0;rr<4;++rr){
        uR[rr] = u_lds[16*ti + 4*h + rr];
        uI[rr] = u_lds[64 + 16*ti + 4*h + rr];
      }
      float ss = 0.f;
#pragma unroll
      for (int jj=0;jj<2;++jj){
        const int tj = 2*tjh + jj;
        Frag b0 = ldbg(UhFL, tj*2+0, lane);
        Frag b1 = ldbg(UhFL, tj*2+1, lane);
        f32x4 acc = {0.f,0.f,0.f,0.f};
        mfma4(a0,b0,acc); mfma4(a1,b1,acc);
        const float urc = u_lds[16*tj + c15], uic = u_lds[64 + 16*tj + c15];
        float xv[4];
#pragma unroll
        for (int rr=0;rr<4;++rr){
          float ov = comp ? (uI[rr]*urc - uR[rr]*uic) : (uR[rr]*urc + uI[rr]*uic);
          xv[rr] = lam*ov + clm*acc[rr];
          ss = fmaf(xv[rr], xv[rr], ss);
        }
        store_tile(O, ti, tj, h, c15, xv);
      }
      ss = wave_sum(ss);
      if (lane == 0) scrN1[w] = ss;
    }
    if (doTail && w < 11){
      if (w < 10){
        float av = ABt[w*64 + lane], bv = ABt[(10+w)*64 + lane];
        float z1a = Zt[w*129 + lane],      z1b = Zt[(10+w)*129 + lane];
        float z2a = Zt[w*129 + 64 + lane], z2b = Zt[(10+w)*129 + 64 + lane];
        float v = av*z1a + bv*z1b + av*z2b - bv*z2a;
        v = wave_sum(v);
        if (lane == 0) scrQ[w] = v;
      } else {
        float v = 0.f;
#pragma unroll
        for (int cc=0; cc<10; ++cc)
          v = fmaf(ABt[(20+cc)*64 + lane], Zt[(20+cc)*129 + lane], v);
        v = wave_sum(v);
        if (lane == 0) scrQ[10] = v;
      }
    }
    __syncthreads();

    // ================= Phase 3: h1 = act(N1)  +  out(t-1) ==================
    if (doMain){
      const int o = w>>3, p = w&7, tj = p&3, t0 = p>>2;   // ti in {t0, t0+2}
      f32x4 acc[2];
      acc[0] = f32x4{0.f,0.f,0.f,0.f}; acc[1] = f32x4{0.f,0.f,0.f,0.f};
#pragma unroll
      for (int m=0;m<2;++m){
        const u32* Ab = m ? B8 : B7;
        const u32* Bb = o ? (m ? B7 : B8) : (m ? B8 : B7);
        const bool neg = (o==1) && (m==1);
#pragma unroll
        for (int kc=0;kc<2;++kc){
          Frag bf  = ldfrag(Bb, GIDX(tj,kc,lane), false);
          Frag af0 = ldfrag(Ab, GIDX(t0,kc,lane), neg);
          mfma4(af0, bf, acc[0]);
          Frag af1 = ldfrag(Ab, GIDX(t0+2,kc,lane), neg);
          mfma4(af1, bf, acc[1]);
        }
      }
      const f32x4* sv = reinterpret_cast<const f32x4*>(scrN1);
      f32x4 s4 = sv[0] + sv[1] + sv[2] + sv[3];
      const float trv = s4[0]+s4[1]+s4[2]+s4[3];
      const float sb = BETA_/trv, cbm = 1.f - BETA_;
      const u32* Nsrc = o ? B8 : B7;
      u32* Od = o ? B1 : B0;
#pragma unroll
      for (int it=0; it<2; ++it){
        const int ti = t0 + 2*it;
        float n[4]; read_tile(Nsrc, ti, tj, h, c15, n);
        float xv[4];
#pragma unroll
        for (int rr=0;rr<4;++rr) xv[rr] = fmaf(sb, acc[it][rr], cbm*n[rr]);
        store_tile(Od, ti, tj, h, c15, xv);
      }
    }
    if (doTail && tid < 10){
      float pnum = dlam*scrQ[tid] + (1.f-dlam)*0.1f;
      float pden = dlam*scrQ[10] + (1.f-dlam);
      out[((size_t)bidx*T_ + (t-1))*C_ + tid] = logf(pnum/pden);
    }
    __syncthreads();

    if (doMain){
      // ============ Phase 4: TX = GEMM(h1,Ux), TH = GEMM(h2,Uh) ============
      {
        const int g2 = w>>3, comp=(w>>2)&1, ti=w&3;
        const u32* A = g2 ? (comp? pH2I : B2) : (comp? B1 : B0);
        const u32* FL = g2 ? UhFL : UxFL;
        u32* O = g2 ? (comp? B7 : B6) : (comp? B5 : pTXR);
        Frag a0 = ldfrag(A, GIDX(ti,0,lane), false);
        Frag a1 = ldfrag(A, GIDX(ti,1,lane), false);
#pragma unroll
        for (int tj=0;tj<4;++tj){
          Frag b0 = ldbg(FL, tj*2+0, lane);
          Frag b1 = ldbg(FL, tj*2+1, lane);
          f32x4 acc = {0.f,0.f,0.f,0.f};
          mfma4(a0,b0,acc); mfma4(a1,b1,acc);
          float xv[4] = {acc[0],acc[1],acc[2],acc[3]};
          store_tile(O, ti, tj, h, c15, xv);
        }
      }
      __syncthreads();

      // ====== Phase 5: N' = lam*GEMM(TX,Ux) + (1-lam)*GEMM(TH,Uh); sumsq ===
      // Register-pressure-staged: X-path frags die before H-path loads.
      {
        const int comp = w>>3, ti=(w>>1)&3, tjh=w&1;
        u32* O = comp ? pH2I : B8;
        f32x4 aX[2], aH[2];
        {
          const u32* AX = comp ? B5 : pTXR;
          Frag ax0 = ldfrag(AX, GIDX(ti,0,lane), false);
          Frag ax1 = ldfrag(AX, GIDX(ti,1,lane), false);
#pragma unroll
          for (int jj=0;jj<2;++jj){
            const int tj = 2*tjh + jj;
            Frag bx0 = ldbg(UxFL, tj*2+0, lane);
            Frag bx1 = ldbg(UxFL, tj*2+1, lane);
            aX[jj] = f32x4{0.f,0.f,0.f,0.f};
            mfma4(ax0,bx0,aX[jj]); mfma4(ax1,bx1,aX[jj]);
          }
        }
        {
          const u32* AH = comp ? B7 : B6;
          Frag ah0 = ldfrag(AH, GIDX(ti,0,lane), false);
          Frag ah1 = ldfrag(AH, GIDX(ti,1,lane), false);
#pragma unroll
          for (int jj=0;jj<2;++jj){
            const int tj = 2*tjh + jj;
            Frag bh0 = ldbg(UhFL, tj*2+0, lane);
            Frag bh1 = ldbg(UhFL, tj*2+1, lane);
            aH[jj] = f32x4{0.f,0.f,0.f,0.f};
            mfma4(ah0,bh0,aH[jj]); mfma4(ah1,bh1,aH[jj]);
          }
        }
        float ss = 0.f;
#pragma unroll
        for (int jj=0;jj<2;++jj){
          const int tj = 2*tjh + jj;
          float xv[4];
#pragma unroll
          for (int rr=0;rr<4;++rr){
            xv[rr] = lam*aX[jj][rr] + clm*aH[jj][rr];
            ss = fmaf(xv[rr], xv[rr], ss);
          }
          store_tile(O, ti, tj, h, c15, xv);
        }
        ss = wave_sum(ss);
        if (lane == 0) scrNp[w] = ss;
      }
      __syncthreads();

      // ================= Phase 6: h2 = act(N') ==============================
      {
        const int o = w>>3, p = w&7, tj = p&3, t0 = p>>2;
        const u32* NPR = B8;
        const u32* NPI = pH2I;
        f32x4 acc[2];
        acc[0] = f32x4{0.f,0.f,0.f,0.f}; acc[1] = f32x4{0.f,0.f,0.f,0.f};
#pragma unroll
        for (int m=0;m<2;++m){
          const u32* Ab = m ? NPI : NPR;
          const u32* Bb = o ? (m ? NPR : NPI) : (m ? NPI : NPR);
          const bool neg = (o==1) && (m==1);
#pragma unroll
          for (int kc=0;kc<2;++kc){
            Frag bf  = ldfrag(Bb, GIDX(tj,kc,lane), false);
            Frag af0 = ldfrag(Ab, GIDX(t0,kc,lane), neg);
            mfma4(af0, bf, acc[0]);
            Frag af1 = ldfrag(Ab, GIDX(t0+2,kc,lane), neg);
            mfma4(af1, bf, acc[1]);
          }
        }
        const f32x4* sv = reinterpret_cast<const f32x4*>(scrNp);
        f32x4 s4 = sv[0] + sv[1] + sv[2] + sv[3];
        const float trv = s4[0]+s4[1]+s4[2]+s4[3];
        const float sb = BETA_/trv, cbm = 1.f - BETA_;
        const u32* Nsrc = o ? NPI : NPR;
        u32* Od = o ? pTXR : B2;    // h2 out: (B2, pTXR)
#pragma unroll
        for (int it=0; it<2; ++it){
          const int ti = t0 + 2*it;
          float n[4]; read_tile(Nsrc, ti, tj, h, c15, n);
          float xv[4];
#pragma unroll
          for (int rr=0;rr<4;++rr) xv[rr] = fmaf(sb, acc[it][rr], cbm*n[rr]);
          store_tile(Od, ti, tj, h, c15, xv);
        }
      }
      __syncthreads();
    }
  }
}

extern "C" void kernel_launch(void* const* d_in, const int* in_sizes, int n_in,
                              void* d_out, int out_size, void* d_ws, size_t ws_size,
                              hipStream_t stream) {
    const float* x       = (const float*)d_in[0];
    const float* amp_w   = (const float*)d_in[1];
    const float* amp_b   = (const float*)d_in[2];
    const float* phase_w = (const float*)d_in[3];
    const float* phase_b = (const float*)d_in[4];
    const float* Ux      = (const float*)d_in[5];
    const float* Uh      = (const float*)d_in[6];
    const float* cl      = (const float*)d_in[7];
    const float* W       = (const float*)d_in[8];
    const float* dl      = (const float*)d_in[9];
    const float* meas    = (const float*)d_in[10];

    float* ws   = (float*)d_ws;
    float* u    = ws;                                  // 128*64*128 f32
    u32*  UhFL  = (u32*)(ws + 1048576);                // 4096
    u32*  UxFL  = UhFL + 4096;                         // 4096
    u32*  AB2FL = UxFL + 4096;                         // 2048
    float* AB2p = (float*)(AB2FL + 2048);              // 2048
    float* ABt  = AB2p + 2048;                         // 1920
    float* out  = (float*)d_out;

    proj_kernel<<<B_ * T_, 64, 0, stream>>>(x, amp_w, amp_b, phase_w, phase_b, Ux, u);
    setup_kernel<<<1, 256, 0, stream>>>(Uh, Ux, W, meas, UhFL, UxFL, AB2FL, AB2p, ABt);
    qrnn_kernel<<<B_, 1024, 0, stream>>>(u, UhFL, UxFL, AB2FL, ABt, cl, dl, out);
}

// Round 5
// 1966.147 us; speedup vs baseline: 1.0984x; 1.0381x over previous
//
#include <hip/hip_runtime.h>
#include <math.h>

#define B_ 64
#define T_ 128
#define INDIM 300
#define D_ 64
#define C_ 10
#define BETA_ 0.8f

typedef unsigned int u32;
typedef _Float16 half8 __attribute__((ext_vector_type(8)));
typedef float f32x4 __attribute__((ext_vector_type(4)));
typedef u32 u32x4 __attribute__((ext_vector_type(4)));
typedef u32 u32x2 __attribute__((ext_vector_type(2)));

// fragment-group index: cb = 16-col block, kc = 32-k block
#define GIDX(cb,kc,ln) ((((cb)*2+(kc))*64) + (ln))

struct Frag { half8 h, l; };

static __device__ __forceinline__ float sigmoidf_(float x){ return 1.f/(1.f+expf(-x)); }

static __device__ __forceinline__ float wave_sum(float v){
#pragma unroll
  for (int off = 32; off > 0; off >>= 1) v += __shfl_down(v, off);
  return v;
}

static __device__ __forceinline__ u32 pkh(_Float16 a, _Float16 b){
  unsigned short ba = __builtin_bit_cast(unsigned short, a);
  unsigned short bb = __builtin_bit_cast(unsigned short, b);
  return (u32)ba | ((u32)bb << 16);
}

static __device__ __forceinline__ void split4(const float* x, u32x2& hw, u32x2& lw){
  _Float16 h0=(_Float16)x[0], h1=(_Float16)x[1], h2=(_Float16)x[2], h3=(_Float16)x[3];
  _Float16 l0=(_Float16)(x[0]-(float)h0), l1=(_Float16)(x[1]-(float)h1);
  _Float16 l2=(_Float16)(x[2]-(float)h2), l3=(_Float16)(x[3]-(float)h3);
  hw[0]=pkh(h0,h1); hw[1]=pkh(h2,h3); lw[0]=pkh(l0,l1); lw[1]=pkh(l2,l3);
}

static __device__ __forceinline__ void up2v(u32 hw, u32 lw, float& v0, float& v1){
  _Float16 h0=__builtin_bit_cast(_Float16,(unsigned short)(hw & 0xffffu));
  _Float16 h1=__builtin_bit_cast(_Float16,(unsigned short)(hw >> 16));
  _Float16 l0=__builtin_bit_cast(_Float16,(unsigned short)(lw & 0xffffu));
  _Float16 l1=__builtin_bit_cast(_Float16,(unsigned short)(lw >> 16));
  v0 = (float)h0 + (float)l0;
  v1 = (float)h1 + (float)l1;
}

// 3-term split product: (ah+al)(bh+bl) ~= ah*bh + ah*bl + al*bh.
// Dropped al*bl term is <= 2^-22 relative -- far below the fp32-accumulation
// noise that dominates absmax (identical 0.015625 in pure-fp32 round 1).
static __device__ __forceinline__ void mfma4(const Frag& a, const Frag& b, f32x4& acc){
  acc = __builtin_amdgcn_mfma_f32_16x16x32_f16(a.h, b.h, acc, 0, 0, 0);
  acc = __builtin_amdgcn_mfma_f32_16x16x32_f16(a.h, b.l, acc, 0, 0, 0);
  acc = __builtin_amdgcn_mfma_f32_16x16x32_f16(a.l, b.h, acc, 0, 0, 0);
}

static __device__ __forceinline__ Frag ldfrag(const u32* buf, int g, bool neg){
  u32x4 a = *reinterpret_cast<const u32x4*>(buf + g*4);
  u32x4 b = *reinterpret_cast<const u32x4*>(buf + 2048 + g*4);
  if (neg){
#pragma unroll
    for (int i=0;i<4;++i){ a[i]^=0x80008000u; b[i]^=0x80008000u; }
  }
  Frag f; f.h = __builtin_bit_cast(half8, a); f.l = __builtin_bit_cast(half8, b);
  return f;
}

static __device__ __forceinline__ Frag ldbg(const u32* FL, int grp, int lane){
  const u32* p = FL + ((size_t)(grp*64 + lane))*8;
  u32x4 a = *reinterpret_cast<const u32x4*>(p);
  u32x4 b = *reinterpret_cast<const u32x4*>(p+4);
  Frag f; f.h = __builtin_bit_cast(half8, a); f.l = __builtin_bit_cast(half8, b);
  return f;
}

static __device__ __forceinline__ void store_tile(u32* O, int ti, int tj, int h, int c15,
                                                  const float* x){
  const int s = h & 1;
  const int lp = c15 + 16*((2*ti + (h>>1)) & 3);
  const int g = GIDX(tj, ti>>1, lp);
  u32x2 hw, lw; split4(x, hw, lw);
  *reinterpret_cast<u32x2*>(O + g*4 + 2*s) = hw;
  *reinterpret_cast<u32x2*>(O + 2048 + g*4 + 2*s) = lw;
}

static __device__ __forceinline__ void read_tile(const u32* O, int ti, int tj, int h, int c15,
                                                 float* n){
  const int s = h & 1;
  const int lp = c15 + 16*((2*ti + (h>>1)) & 3);
  const int g = GIDX(tj, ti>>1, lp);
  u32x2 nh = *reinterpret_cast<const u32x2*>(O + g*4 + 2*s);
  u32x2 nl = *reinterpret_cast<const u32x2*>(O + 2048 + g*4 + 2*s);
  up2v(nh[0],nl[0],n[0],n[1]); up2v(nh[1],nl[1],n[2],n[3]);
}

// ---------------- Kernel A: projections + s + u = Ux @ s -------------------
__global__ __launch_bounds__(64) void proj_kernel(
    const float* __restrict__ x, const float* __restrict__ amp_w,
    const float* __restrict__ amp_b, const float* __restrict__ phase_w,
    const float* __restrict__ phase_b, const float* __restrict__ Ux,
    float* __restrict__ u_out) {
    __shared__ float xr[INDIM];
    __shared__ float s_r[D_], s_i[D_];
    const int bt = blockIdx.x;
    const int b = bt / T_, t = bt % T_;
    const float* xrow = x + (size_t)bt * INDIM;
    for (int i = threadIdx.x; i < INDIM; i += 64) xr[i] = xrow[i];
    __syncthreads();
    const int d = threadIdx.x;
    float a = amp_b[d], p = phase_b[d];
    for (int k = 0; k < INDIM; ++k) {
        float xv = xr[k];
        a = fmaf(xv, amp_w[k * D_ + d], a);
        p = fmaf(xv, phase_w[k * D_ + d], p);
    }
    float sq = a * a;
    #pragma unroll
    for (int off = 32; off > 0; off >>= 1) sq += __shfl_xor(sq, off);
    float an = a / sqrtf(sq);
    s_r[d] = an * cosf(p);
    s_i[d] = an * sinf(p);
    __syncthreads();
    float ur = 0.f, ui = 0.f;
    const float* Uxrow = Ux + d * D_;
    for (int e = 0; e < D_; ++e) {
        float uv = Uxrow[e];
        ur = fmaf(uv, s_r[e], ur);
        ui = fmaf(uv, s_i[e], ui);
    }
    float* ub = u_out + ((size_t)t * B_ + b) * 128;
    ub[d] = ur;
    ub[64 + d] = ui;
}

// ---------------- Kernel B: operand-fragment precompute --------------------
__global__ __launch_bounds__(256) void setup_kernel(
    const float* __restrict__ Uh, const float* __restrict__ Ux,
    const float* __restrict__ W, const float* __restrict__ meas,
    u32* __restrict__ UhFL, u32* __restrict__ UxFL,
    u32* __restrict__ AB2FL, float* __restrict__ AB2p, float* __restrict__ ABt)
{
  const int tid = threadIdx.x;
  for (int wi = tid; wi < 4096; wi += 256){
    int off = wi & 7, g = wi >> 3;
    int lane_ = g & 63, cbkc = g >> 6;
    int cb = cbkc >> 1, kc = cbkc & 1;
    int wq = off & 3; bool isHi = off < 4;
    int k0 = 32*kc + 8*(lane_>>4) + 2*wq;
    int c  = 16*cb + (lane_&15);
    {
      float x0 = Uh[c*64 + k0], x1 = Uh[c*64 + k0 + 1];
      _Float16 h0=(_Float16)x0, h1=(_Float16)x1;
      UhFL[wi] = isHi ? pkh(h0,h1)
                      : pkh((_Float16)(x0-(float)h0), (_Float16)(x1-(float)h1));
    }
    {
      float x0 = Ux[c*64 + k0], x1 = Ux[c*64 + k0 + 1];
      _Float16 h0=(_Float16)x0, h1=(_Float16)x1;
      UxFL[wi] = isHi ? pkh(h0,h1)
                      : pkh((_Float16)(x0-(float)h0), (_Float16)(x1-(float)h1));
    }
  }
  __shared__ float invn[C_];
  if (tid < C_) {
    float s = 0.f;
    for (int j = 0; j < C_; ++j) {
      float vr = meas[(tid * C_ + j) * 2], vi = meas[(tid * C_ + j) * 2 + 1];
      s += vr * vr + vi * vi;
    }
    invn[tid] = 1.0f / sqrtf(s);
  }
  __syncthreads();
  for (int i = tid; i < D_ * 32; i += 256) {
    int dd = i >> 5, c = i & 31;
    float v = 0.f;
    if (c < C_) {
      float acc = 0.f;
      for (int j = 0; j < C_; ++j) acc = fmaf(W[dd * C_ + j], meas[(c * C_ + j) * 2], acc);
      v = acc * invn[c];
    } else if (c < 2 * C_) {
      int k = c - C_;
      float acc = 0.f;
      for (int j = 0; j < C_; ++j) acc = fmaf(W[dd * C_ + j], meas[(k * C_ + j) * 2 + 1], acc);
      v = acc * invn[k];
    } else if (c < 3 * C_) {
      v = W[dd * C_ + (c - 2 * C_)];
    }
    AB2p[i] = v;
  }
  __syncthreads();
  // AB2FL fragment layout
  for (int wi = tid; wi < 2048; wi += 256){
    int off = wi & 7, g = wi >> 3;
    int lane_ = g & 63, cbkc = g >> 6;
    int cb = cbkc >> 1, kc = cbkc & 1;
    int wq = off & 3; bool isHi = off < 4;
    int k0 = 32*kc + 8*(lane_>>4) + 2*wq;
    int c  = 16*cb + (lane_&15);
    float x0 = AB2p[k0*32 + c], x1 = AB2p[(k0+1)*32 + c];
    _Float16 h0=(_Float16)x0, h1=(_Float16)x1;
    AB2FL[wi] = isHi ? pkh(h0,h1)
                     : pkh((_Float16)(x0-(float)h0), (_Float16)(x1-(float)h1));
  }
  // ABt[c][d] = AB2p[d][c], c<30 (coalesced meas reads)
  for (int i = tid; i < 30*64; i += 256){
    int c = i >> 6, d = i & 63;
    ABt[i] = AB2p[d*32 + c];
  }
}

// ---------------- Kernel C: fused 2-layer scan + dense + measurement -------
// Occupancy pinning: LDS (145 KB) already limits to 1 block/CU = 16 waves =
// 4 waves/EU. waves_per_eu(4,4) makes the register allocator budget for
// exactly that (512/4 = 128 VGPRs) instead of its default 8-waves/EU target
// (64 VGPRs) which caused pure-loss spilling (WRITE_SIZE 16 MB, rounds 3-4).
__global__ __attribute__((amdgpu_flat_work_group_size(1024,1024),
                          amdgpu_waves_per_eu(4,4)))
void qrnn_kernel(
    const float* __restrict__ u_in,
    const u32* __restrict__ UhFL, const u32* __restrict__ UxFL,
    const u32* __restrict__ AB2FL, const float* __restrict__ ABt,
    const float* __restrict__ cell_lambda, const float* __restrict__ dense_lambda,
    float* __restrict__ out)
{
  // 9 matrix buffers, each 4096 u32 (hi 2048 | lo 2048)
  __shared__ __align__(16) u32 ds[9*4096];
  __shared__ float u_lds[128];
  __shared__ float scrN1[16], scrNp[16], scrQ[12];

  const int tid = threadIdx.x;
  const int lane = tid & 63;
  const int w = tid >> 6;          // 0..15
  const int h = lane >> 4;
  const int c15 = lane & 15;
  const int bidx = blockIdx.x;
  const float lam = sigmoidf_(cell_lambda[0]);
  const float clm = 1.f - lam;
  const float dlam = sigmoidf_(dense_lambda[0]);

  u32* const B0 = ds + 0*4096;   // h1R
  u32* const B1 = ds + 1*4096;   // h1I
  u32* const B2 = ds + 2*4096;   // h2R (fixed)
  u32* const B3 = ds + 3*4096;
  u32* const B4 = ds + 4*4096;
  u32* const B5 = ds + 5*4096;   // T1I / TXI
  u32* const B6 = ds + 6*4096;   // Zt (fp32 30x129) / THR
  u32* const B7 = ds + 7*4096;   // N1R / THI
  u32* const B8 = ds + 8*4096;   // N1I / N'R
  float* const Zt = reinterpret_cast<float*>(B6);

  // ---- init h1 = h2 = I/64 ----
  const u32 one64 = (u32)__builtin_bit_cast(unsigned short, (_Float16)0.015625f);
  for (int wi = tid; wi < 4096; wi += 1024){
    u32 vR = 0u;
    if (wi < 2048){
      int g = wi >> 2, wq = wi & 3;
      int lane_ = g & 63, cbkc = g >> 6;
      int cb = cbkc >> 1, kc = cbkc & 1;
      int k0 = 32*kc + 8*(lane_>>4) + 2*wq;
      int c = 16*cb + (lane_&15);
      if (k0 == c)   vR |= one64;
      if (k0+1 == c) vR |= (one64 << 16);
    }
    B0[wi] = vR; B2[wi] = vR; B1[wi] = 0u; B3[wi] = 0u;
  }
  __syncthreads();

  for (int t = 0; t <= T_; ++t){
    const bool doMain = (t < T_);
    const bool doTail = (t > 0);
    const int par = t & 1;
    u32* const pH2I = par ? B4 : B3;   // h2I in-state; also N' I dest
    u32* const pTXR = par ? B3 : B4;   // T1R/TXR dest; also h2I out-state

    // ================= Phase 1: T1 = GEMM(h1,Uh)  +  dense(t-1) ===========
    if (doMain){
      if (tid < 128) u_lds[tid] = u_in[((size_t)t*B_ + bidx)*128 + tid];
      const int comp = w>>3, ti=(w>>1)&3, tjh=w&1;
      const u32* A = comp ? B1 : B0;
      Frag a0 = ldfrag(A, GIDX(ti,0,lane), false);
      Frag a1 = ldfrag(A, GIDX(ti,1,lane), false);
      u32* O = comp ? B5 : pTXR;
#pragma unroll
      for (int jj=0;jj<2;++jj){
        const int tj = 2*tjh + jj;
        Frag b0 = ldbg(UhFL, tj*2+0, lane);
        Frag b1 = ldbg(UhFL, tj*2+1, lane);
        f32x4 acc = {0.f,0.f,0.f,0.f};
        mfma4(a0,b0,acc); mfma4(a1,b1,acc);
        float xv[4] = {acc[0],acc[1],acc[2],acc[3]};
        store_tile(O, ti, tj, h, c15, xv);
      }
    }
    if (doTail){
      const int rb = w>>1, cz = w&1, cb = rb&3;
      const u32* A = (rb<4) ? B2 : pH2I;
      Frag a0 = ldfrag(A, GIDX(cb,0,lane), false);
      Frag a1 = ldfrag(A, GIDX(cb,1,lane), false);
      Frag b0 = ldbg(AB2FL, cz*2+0, lane);
      Frag b1 = ldbg(AB2FL, cz*2+1, lane);
      f32x4 za = {0.f,0.f,0.f,0.f};
      mfma4(a0,b0,za); mfma4(a1,b1,za);
      const int c = 16*cz + c15;
      if (c < 30){
        float* zp = Zt + c*129 + 16*rb + 4*h;
#pragma unroll
        for (int rr=0;rr<4;++rr) zp[rr] = za[rr];
      }
    }
    __syncthreads();

    // ===== Phase 2: N1 = lam*outer(u) + (1-lam)*GEMM(T1,Uh); sumsq  + meas =
    if (doMain){
      const int comp = w>>3, ti=(w>>1)&3, tjh=w&1;
      const u32* A = comp ? B5 : pTXR;
      Frag a0 = ldfrag(A, GIDX(ti,0,lane), false);
      Frag a1 = ldfrag(A, GIDX(ti,1,lane), false);
      u32* O = comp ? B8 : B7;
      float uR[4], uI[4];
#pragma unroll
      for (int rr=0;rr<4;++rr){
        uR[rr] = u_lds[16*ti + 4*h + rr];
        uI[rr] = u_lds[64 + 16*ti + 4*h + rr];
      }
      float ss = 0.f;
#pragma unroll
      for (int jj=0;jj<2;++jj){
        const int tj = 2*tjh + jj;
        Frag b0 = ldbg(UhFL, tj*2+0, lane);
        Frag b1 = ldbg(UhFL, tj*2+1, lane);
        f32x4 acc = {0.f,0.f,0.f,0.f};
        mfma4(a0,b0,acc); mfma4(a1,b1,acc);
        const float urc = u_lds[16*tj + c15], uic = u_lds[64 + 16*tj + c15];
        float xv[4];
#pragma unroll
        for (int rr=0;rr<4;++rr){
          float ov = comp ? (uI[rr]*urc - uR[rr]*uic) : (uR[rr]*urc + uI[rr]*uic);
          xv[rr] = lam*ov + clm*acc[rr];
          ss = fmaf(xv[rr], xv[rr], ss);
        }
        store_tile(O, ti, tj, h, c15, xv);
      }
      ss = wave_sum(ss);
      if (lane == 0) scrN1[w] = ss;
    }
    if (doTail && w < 11){
      if (w < 10){
        float av = ABt[w*64 + lane], bv = ABt[(10+w)*64 + lane];
        float z1a = Zt[w*129 + lane],      z1b = Zt[(10+w)*129 + lane];
        float z2a = Zt[w*129 + 64 + lane], z2b = Zt[(10+w)*129 + 64 + lane];
        float v = av*z1a + bv*z1b + av*z2b - bv*z2a;
        v = wave_sum(v);
        if (lane == 0) scrQ[w] = v;
      } else {
        float v = 0.f;
#pragma unroll
        for (int cc=0; cc<10; ++cc)
          v = fmaf(ABt[(20+cc)*64 + lane], Zt[(20+cc)*129 + lane], v);
        v = wave_sum(v);
        if (lane == 0) scrQ[10] = v;
      }
    }
    __syncthreads();

    // ================= Phase 3: h1 = act(N1)  +  out(t-1) ==================
    if (doMain){
      const int o = w>>3, p = w&7, tj = p&3, t0 = p>>2;   // ti in {t0, t0+2}
      f32x4 acc[2];
      acc[0] = f32x4{0.f,0.f,0.f,0.f}; acc[1] = f32x4{0.f,0.f,0.f,0.f};
#pragma unroll
      for (int m=0;m<2;++m){
        const u32* Ab = m ? B8 : B7;
        const u32* Bb = o ? (m ? B7 : B8) : (m ? B8 : B7);
        const bool neg = (o==1) && (m==1);
#pragma unroll
        for (int kc=0;kc<2;++kc){
          Frag bf  = ldfrag(Bb, GIDX(tj,kc,lane), false);
          Frag af0 = ldfrag(Ab, GIDX(t0,kc,lane), neg);
          mfma4(af0, bf, acc[0]);
          Frag af1 = ldfrag(Ab, GIDX(t0+2,kc,lane), neg);
          mfma4(af1, bf, acc[1]);
        }
      }
      const f32x4* sv = reinterpret_cast<const f32x4*>(scrN1);
      f32x4 s4 = sv[0] + sv[1] + sv[2] + sv[3];
      const float trv = s4[0]+s4[1]+s4[2]+s4[3];
      const float sb = BETA_/trv, cbm = 1.f - BETA_;
      const u32* Nsrc = o ? B8 : B7;
      u32* Od = o ? B1 : B0;
#pragma unroll
      for (int it=0; it<2; ++it){
        const int ti = t0 + 2*it;
        float n[4]; read_tile(Nsrc, ti, tj, h, c15, n);
        float xv[4];
#pragma unroll
        for (int rr=0;rr<4;++rr) xv[rr] = fmaf(sb, acc[it][rr], cbm*n[rr]);
        store_tile(Od, ti, tj, h, c15, xv);
      }
    }
    if (doTail && tid < 10){
      float pnum = dlam*scrQ[tid] + (1.f-dlam)*0.1f;
      float pden = dlam*scrQ[10] + (1.f-dlam);
      out[((size_t)bidx*T_ + (t-1))*C_ + tid] = logf(pnum/pden);
    }
    __syncthreads();

    if (doMain){
      // ============ Phase 4: TX = GEMM(h1,Ux), TH = GEMM(h2,Uh) ============
      {
        const int g2 = w>>3, comp=(w>>2)&1, ti=w&3;
        const u32* A = g2 ? (comp? pH2I : B2) : (comp? B1 : B0);
        const u32* FL = g2 ? UhFL : UxFL;
        u32* O = g2 ? (comp? B7 : B6) : (comp? B5 : pTXR);
        Frag a0 = ldfrag(A, GIDX(ti,0,lane), false);
        Frag a1 = ldfrag(A, GIDX(ti,1,lane), false);
#pragma unroll
        for (int tj=0;tj<4;++tj){
          Frag b0 = ldbg(FL, tj*2+0, lane);
          Frag b1 = ldbg(FL, tj*2+1, lane);
          f32x4 acc = {0.f,0.f,0.f,0.f};
          mfma4(a0,b0,acc); mfma4(a1,b1,acc);
          float xv[4] = {acc[0],acc[1],acc[2],acc[3]};
          store_tile(O, ti, tj, h, c15, xv);
        }
      }
      __syncthreads();

      // ====== Phase 5: N' = lam*GEMM(TX,Ux) + (1-lam)*GEMM(TH,Uh); sumsq ===
      // Register-pressure-staged: X-path frags die before H-path loads.
      {
        const int comp = w>>3, ti=(w>>1)&3, tjh=w&1;
        u32* O = comp ? pH2I : B8;
        f32x4 aX[2], aH[2];
        {
          const u32* AX = comp ? B5 : pTXR;
          Frag ax0 = ldfrag(AX, GIDX(ti,0,lane), false);
          Frag ax1 = ldfrag(AX, GIDX(ti,1,lane), false);
#pragma unroll
          for (int jj=0;jj<2;++jj){
            const int tj = 2*tjh + jj;
            Frag bx0 = ldbg(UxFL, tj*2+0, lane);
            Frag bx1 = ldbg(UxFL, tj*2+1, lane);
            aX[jj] = f32x4{0.f,0.f,0.f,0.f};
            mfma4(ax0,bx0,aX[jj]); mfma4(ax1,bx1,aX[jj]);
          }
        }
        {
          const u32* AH = comp ? B7 : B6;
          Frag ah0 = ldfrag(AH, GIDX(ti,0,lane), false);
          Frag ah1 = ldfrag(AH, GIDX(ti,1,lane), false);
#pragma unroll
          for (int jj=0;jj<2;++jj){
            const int tj = 2*tjh + jj;
            Frag bh0 = ldbg(UhFL, tj*2+0, lane);
            Frag bh1 = ldbg(UhFL, tj*2+1, lane);
            aH[jj] = f32x4{0.f,0.f,0.f,0.f};
            mfma4(ah0,bh0,aH[jj]); mfma4(ah1,bh1,aH[jj]);
          }
        }
        float ss = 0.f;
#pragma unroll
        for (int jj=0;jj<2;++jj){
          const int tj = 2*tjh + jj;
          float xv[4];
#pragma unroll
          for (int rr=0;rr<4;++rr){
            xv[rr] = lam*aX[jj][rr] + clm*aH[jj][rr];
            ss = fmaf(xv[rr], xv[rr], ss);
          }
          store_tile(O, ti, tj, h, c15, xv);
        }
        ss = wave_sum(ss);
        if (lane == 0) scrNp[w] = ss;
      }
      __syncthreads();

      // ================= Phase 6: h2 = act(N') ==============================
      {
        const int o = w>>3, p = w&7, tj = p&3, t0 = p>>2;
        const u32* NPR = B8;
        const u32* NPI = pH2I;
        f32x4 acc[2];
        acc[0] = f32x4{0.f,0.f,0.f,0.f}; acc[1] = f32x4{0.f,0.f,0.f,0.f};
#pragma unroll
        for (int m=0;m<2;++m){
          const u32* Ab = m ? NPI : NPR;
          const u32* Bb = o ? (m ? NPR : NPI) : (m ? NPI : NPR);
          const bool neg = (o==1) && (m==1);
#pragma unroll
          for (int kc=0;kc<2;++kc){
            Frag bf  = ldfrag(Bb, GIDX(tj,kc,lane), false);
            Frag af0 = ldfrag(Ab, GIDX(t0,kc,lane), neg);
            mfma4(af0, bf, acc[0]);
            Frag af1 = ldfrag(Ab, GIDX(t0+2,kc,lane), neg);
            mfma4(af1, bf, acc[1]);
          }
        }
        const f32x4* sv = reinterpret_cast<const f32x4*>(scrNp);
        f32x4 s4 = sv[0] + sv[1] + sv[2] + sv[3];
        const float trv = s4[0]+s4[1]+s4[2]+s4[3];
        const float sb = BETA_/trv, cbm = 1.f - BETA_;
        const u32* Nsrc = o ? NPI : NPR;
        u32* Od = o ? pTXR : B2;    // h2 out: (B2, pTXR)
#pragma unroll
        for (int it=0; it<2; ++it){
          const int ti = t0 + 2*it;
          float n[4]; read_tile(Nsrc, ti, tj, h, c15, n);
          float xv[4];
#pragma unroll
          for (int rr=0;rr<4;++rr) xv[rr] = fmaf(sb, acc[it][rr], cbm*n[rr]);
          store_tile(Od, ti, tj, h, c15, xv);
        }
      }
      __syncthreads();
    }
  }
}

extern "C" void kernel_launch(void* const* d_in, const int* in_sizes, int n_in,
                              void* d_out, int out_size, void* d_ws, size_t ws_size,
                              hipStream_t stream) {
    const float* x       = (const float*)d_in[0];
    const float* amp_w   = (const float*)d_in[1];
    const float* amp_b   = (const float*)d_in[2];
    const float* phase_w = (const float*)d_in[3];
    const float* phase_b = (const float*)d_in[4];
    const float* Ux      = (const float*)d_in[5];
    const float* Uh      = (const float*)d_in[6];
    const float* cl      = (const float*)d_in[7];
    const float* W       = (const float*)d_in[8];
    const float* dl      = (const float*)d_in[9];
    const float* meas    = (const float*)d_in[10];

    float* ws   = (float*)d_ws;
    float* u    = ws;                                  // 128*64*128 f32
    u32*  UhFL  = (u32*)(ws + 1048576);                // 4096
    u32*  UxFL  = UhFL + 4096;                         // 4096
    u32*  AB2FL = UxFL + 4096;                         // 2048
    float* AB2p = (float*)(AB2FL + 2048);              // 2048
    float* ABt  = AB2p + 2048;                         // 1920
    float* out  = (float*)d_out;

    proj_kernel<<<B_ * T_, 64, 0, stream>>>(x, amp_w, amp_b, phase_w, phase_b, Ux, u);
    setup_kernel<<<1, 256, 0, stream>>>(Uh, Ux, W, meas, UhFL, UxFL, AB2FL, AB2p, ABt);
    qrnn_kernel<<<B_, 1024, 0, stream>>>(u, UhFL, UxFL, AB2FL, ABt, cl, dl, out);
}

// Round 6
// 1662.412 us; speedup vs baseline: 1.2991x; 1.1827x over previous
//
#include <hip/hip_runtime.h>
#include <math.h>

#define B_ 64
#define T_ 128
#define INDIM 300
#define D_ 64
#define C_ 10
#define BETA_ 0.8f

typedef unsigned int u32;
typedef _Float16 half8 __attribute__((ext_vector_type(8)));
typedef float f32x4 __attribute__((ext_vector_type(4)));
typedef u32 u32x4 __attribute__((ext_vector_type(4)));
typedef u32 u32x2 __attribute__((ext_vector_type(2)));

// fragment-group index: cb = 16-col block, kc = 32-k block
#define GIDX(cb,kc,ln) ((((cb)*2+(kc))*64) + (ln))

struct Frag { half8 h, l; };

static __device__ __forceinline__ float sigmoidf_(float x){ return 1.f/(1.f+expf(-x)); }

static __device__ __forceinline__ float wave_sum(float v){
#pragma unroll
  for (int off = 32; off > 0; off >>= 1) v += __shfl_down(v, off);
  return v;
}

static __device__ __forceinline__ u32 pkh(_Float16 a, _Float16 b){
  unsigned short ba = __builtin_bit_cast(unsigned short, a);
  unsigned short bb = __builtin_bit_cast(unsigned short, b);
  return (u32)ba | ((u32)bb << 16);
}

static __device__ __forceinline__ void split4(const float* x, u32x2& hw, u32x2& lw){
  _Float16 h0=(_Float16)x[0], h1=(_Float16)x[1], h2=(_Float16)x[2], h3=(_Float16)x[3];
  _Float16 l0=(_Float16)(x[0]-(float)h0), l1=(_Float16)(x[1]-(float)h1);
  _Float16 l2=(_Float16)(x[2]-(float)h2), l3=(_Float16)(x[3]-(float)h3);
  hw[0]=pkh(h0,h1); hw[1]=pkh(h2,h3); lw[0]=pkh(l0,l1); lw[1]=pkh(l2,l3);
}

static __device__ __forceinline__ void up2v(u32 hw, u32 lw, float& v0, float& v1){
  _Float16 h0=__builtin_bit_cast(_Float16,(unsigned short)(hw & 0xffffu));
  _Float16 h1=__builtin_bit_cast(_Float16,(unsigned short)(hw >> 16));
  _Float16 l0=__builtin_bit_cast(_Float16,(unsigned short)(lw & 0xffffu));
  _Float16 l1=__builtin_bit_cast(_Float16,(unsigned short)(lw >> 16));
  v0 = (float)h0 + (float)l0;
  v1 = (float)h1 + (float)l1;
}

// 3-term split product: (ah+al)(bh+bl) ~= ah*bh + ah*bl + al*bh.
static __device__ __forceinline__ void mfma4(const Frag& a, const Frag& b, f32x4& acc){
  acc = __builtin_amdgcn_mfma_f32_16x16x32_f16(a.h, b.h, acc, 0, 0, 0);
  acc = __builtin_amdgcn_mfma_f32_16x16x32_f16(a.h, b.l, acc, 0, 0, 0);
  acc = __builtin_amdgcn_mfma_f32_16x16x32_f16(a.l, b.h, acc, 0, 0, 0);
}

static __device__ __forceinline__ Frag ldfrag(const u32* buf, int g, bool neg){
  u32x4 a = *reinterpret_cast<const u32x4*>(buf + g*4);
  u32x4 b = *reinterpret_cast<const u32x4*>(buf + 2048 + g*4);
  if (neg){
#pragma unroll
    for (int i=0;i<4;++i){ a[i]^=0x80008000u; b[i]^=0x80008000u; }
  }
  Frag f; f.h = __builtin_bit_cast(half8, a); f.l = __builtin_bit_cast(half8, b);
  return f;
}

static __device__ __forceinline__ Frag ldbg(const u32* FL, int grp, int lane){
  const u32* p = FL + ((size_t)(grp*64 + lane))*8;
  u32x4 a = *reinterpret_cast<const u32x4*>(p);
  u32x4 b = *reinterpret_cast<const u32x4*>(p+4);
  Frag f; f.h = __builtin_bit_cast(half8, a); f.l = __builtin_bit_cast(half8, b);
  return f;
}

static __device__ __forceinline__ void store_tile(u32* O, int ti, int tj, int h, int c15,
                                                  const float* x){
  const int s = h & 1;
  const int lp = c15 + 16*((2*ti + (h>>1)) & 3);
  const int g = GIDX(tj, ti>>1, lp);
  u32x2 hw, lw; split4(x, hw, lw);
  *reinterpret_cast<u32x2*>(O + g*4 + 2*s) = hw;
  *reinterpret_cast<u32x2*>(O + 2048 + g*4 + 2*s) = lw;
}

static __device__ __forceinline__ void read_tile(const u32* O, int ti, int tj, int h, int c15,
                                                 float* n){
  const int s = h & 1;
  const int lp = c15 + 16*((2*ti + (h>>1)) & 3);
  const int g = GIDX(tj, ti>>1, lp);
  u32x2 nh = *reinterpret_cast<const u32x2*>(O + g*4 + 2*s);
  u32x2 nl = *reinterpret_cast<const u32x2*>(O + 2048 + g*4 + 2*s);
  up2v(nh[0],nl[0],n[0],n[1]); up2v(nh[1],nl[1],n[2],n[3]);
}

// ---------------- Kernel A: projections + s + u = Ux @ s -------------------
__global__ __launch_bounds__(64) void proj_kernel(
    const float* __restrict__ x, const float* __restrict__ amp_w,
    const float* __restrict__ amp_b, const float* __restrict__ phase_w,
    const float* __restrict__ phase_b, const float* __restrict__ Ux,
    float* __restrict__ u_out) {
    __shared__ float xr[INDIM];
    __shared__ float s_r[D_], s_i[D_];
    const int bt = blockIdx.x;
    const int b = bt / T_, t = bt % T_;
    const float* xrow = x + (size_t)bt * INDIM;
    for (int i = threadIdx.x; i < INDIM; i += 64) xr[i] = xrow[i];
    __syncthreads();
    const int d = threadIdx.x;
    float a = amp_b[d], p = phase_b[d];
    for (int k = 0; k < INDIM; ++k) {
        float xv = xr[k];
        a = fmaf(xv, amp_w[k * D_ + d], a);
        p = fmaf(xv, phase_w[k * D_ + d], p);
    }
    float sq = a * a;
    #pragma unroll
    for (int off = 32; off > 0; off >>= 1) sq += __shfl_xor(sq, off);
    float an = a / sqrtf(sq);
    s_r[d] = an * cosf(p);
    s_i[d] = an * sinf(p);
    __syncthreads();
    float ur = 0.f, ui = 0.f;
    const float* Uxrow = Ux + d * D_;
    for (int e = 0; e < D_; ++e) {
        float uv = Uxrow[e];
        ur = fmaf(uv, s_r[e], ur);
        ui = fmaf(uv, s_i[e], ui);
    }
    float* ub = u_out + ((size_t)t * B_ + b) * 128;
    ub[d] = ur;
    ub[64 + d] = ui;
}

// ---------------- Kernel B: operand-fragment precompute --------------------
__global__ __launch_bounds__(256) void setup_kernel(
    const float* __restrict__ Uh, const float* __restrict__ Ux,
    const float* __restrict__ W, const float* __restrict__ meas,
    u32* __restrict__ UhFL, u32* __restrict__ UxFL,
    u32* __restrict__ AB2FL, float* __restrict__ AB2p, float* __restrict__ ABt)
{
  const int tid = threadIdx.x;
  for (int wi = tid; wi < 4096; wi += 256){
    int off = wi & 7, g = wi >> 3;
    int lane_ = g & 63, cbkc = g >> 6;
    int cb = cbkc >> 1, kc = cbkc & 1;
    int wq = off & 3; bool isHi = off < 4;
    int k0 = 32*kc + 8*(lane_>>4) + 2*wq;
    int c  = 16*cb + (lane_&15);
    {
      float x0 = Uh[c*64 + k0], x1 = Uh[c*64 + k0 + 1];
      _Float16 h0=(_Float16)x0, h1=(_Float16)x1;
      UhFL[wi] = isHi ? pkh(h0,h1)
                      : pkh((_Float16)(x0-(float)h0), (_Float16)(x1-(float)h1));
    }
    {
      float x0 = Ux[c*64 + k0], x1 = Ux[c*64 + k0 + 1];
      _Float16 h0=(_Float16)x0, h1=(_Float16)x1;
      UxFL[wi] = isHi ? pkh(h0,h1)
                      : pkh((_Float16)(x0-(float)h0), (_Float16)(x1-(float)h1));
    }
  }
  __shared__ float invn[C_];
  if (tid < C_) {
    float s = 0.f;
    for (int j = 0; j < C_; ++j) {
      float vr = meas[(tid * C_ + j) * 2], vi = meas[(tid * C_ + j) * 2 + 1];
      s += vr * vr + vi * vi;
    }
    invn[tid] = 1.0f / sqrtf(s);
  }
  __syncthreads();
  for (int i = tid; i < D_ * 32; i += 256) {
    int dd = i >> 5, c = i & 31;
    float v = 0.f;
    if (c < C_) {
      float acc = 0.f;
      for (int j = 0; j < C_; ++j) acc = fmaf(W[dd * C_ + j], meas[(c * C_ + j) * 2], acc);
      v = acc * invn[c];
    } else if (c < 2 * C_) {
      int k = c - C_;
      float acc = 0.f;
      for (int j = 0; j < C_; ++j) acc = fmaf(W[dd * C_ + j], meas[(k * C_ + j) * 2 + 1], acc);
      v = acc * invn[k];
    } else if (c < 3 * C_) {
      v = W[dd * C_ + (c - 2 * C_)];
    }
    AB2p[i] = v;
  }
  __syncthreads();
  // AB2FL fragment layout
  for (int wi = tid; wi < 2048; wi += 256){
    int off = wi & 7, g = wi >> 3;
    int lane_ = g & 63, cbkc = g >> 6;
    int cb = cbkc >> 1, kc = cbkc & 1;
    int wq = off & 3; bool isHi = off < 4;
    int k0 = 32*kc + 8*(lane_>>4) + 2*wq;
    int c  = 16*cb + (lane_&15);
    float x0 = AB2p[k0*32 + c], x1 = AB2p[(k0+1)*32 + c];
    _Float16 h0=(_Float16)x0, h1=(_Float16)x1;
    AB2FL[wi] = isHi ? pkh(h0,h1)
                     : pkh((_Float16)(x0-(float)h0), (_Float16)(x1-(float)h1));
  }
  // ABt[c][d] = AB2p[d][c], c<30 (coalesced meas reads)
  for (int i = tid; i < 30*64; i += 256){
    int c = i >> 6, d = i & 63;
    ABt[i] = AB2p[d*32 + c];
  }
}

// ---------------- Kernel C: fused 2-layer scan + dense + measurement -------
// 512 threads (8 waves): the empirically-proven 128-VGPR configuration
// (round 2: VGPR_Count=128). 1024-thread blocks get a hard 64-VGPR budget
// from the allocator regardless of launch_bounds/waves_per_eu attributes
// (rounds 3-5: VGPR 64, 16 MB scratch-spill writes). Do not go back to 1024.
__global__ __launch_bounds__(512) void qrnn_kernel(
    const float* __restrict__ u_in,
    const u32* __restrict__ UhFL, const u32* __restrict__ UxFL,
    const u32* __restrict__ AB2FL, const float* __restrict__ ABt,
    const float* __restrict__ cell_lambda, const float* __restrict__ dense_lambda,
    float* __restrict__ out)
{
  // 9 matrix buffers, each 4096 u32 (hi 2048 | lo 2048)
  __shared__ __align__(16) u32 ds[9*4096];
  __shared__ float u_lds[128];
  __shared__ float scrN1[8], scrNp[8], scrQ[12];

  const int tid = threadIdx.x;
  const int lane = tid & 63;
  const int w = tid >> 6;          // 0..7
  const int h = lane >> 4;
  const int c15 = lane & 15;
  const int bidx = blockIdx.x;
  const float lam = sigmoidf_(cell_lambda[0]);
  const float clm = 1.f - lam;
  const float dlam = sigmoidf_(dense_lambda[0]);

  u32* const B0 = ds + 0*4096;   // h1R
  u32* const B1 = ds + 1*4096;   // h1I
  u32* const B2 = ds + 2*4096;   // h2R (fixed)
  u32* const B3 = ds + 3*4096;
  u32* const B4 = ds + 4*4096;
  u32* const B5 = ds + 5*4096;   // T1I / TXI
  u32* const B6 = ds + 6*4096;   // Zt (fp32 30x129) / THR
  u32* const B7 = ds + 7*4096;   // N1R / THI
  u32* const B8 = ds + 8*4096;   // N1I / N'R
  float* const Zt = reinterpret_cast<float*>(B6);

  // ---- init h1 = h2 = I/64 ----
  const u32 one64 = (u32)__builtin_bit_cast(unsigned short, (_Float16)0.015625f);
  for (int wi = tid; wi < 4096; wi += 512){
    u32 vR = 0u;
    if (wi < 2048){
      int g = wi >> 2, wq = wi & 3;
      int lane_ = g & 63, cbkc = g >> 6;
      int cb = cbkc >> 1, kc = cbkc & 1;
      int k0 = 32*kc + 8*(lane_>>4) + 2*wq;
      int c = 16*cb + (lane_&15);
      if (k0 == c)   vR |= one64;
      if (k0+1 == c) vR |= (one64 << 16);
    }
    B0[wi] = vR; B2[wi] = vR; B1[wi] = 0u; B3[wi] = 0u;
  }
  __syncthreads();

  for (int t = 0; t <= T_; ++t){
    const bool doMain = (t < T_);
    const bool doTail = (t > 0);
    const int par = t & 1;
    u32* const pH2I = par ? B4 : B3;   // h2I in-state; also N' I dest
    u32* const pTXR = par ? B3 : B4;   // T1R/TXR dest; also h2I out-state

    // ================= Phase 1: T1 = GEMM(h1,Uh)  +  dense(t-1) ===========
    if (doMain){
      if (tid < 128) u_lds[tid] = u_in[((size_t)t*B_ + bidx)*128 + tid];
      const int comp = w>>2, ti = w&3;
      const u32* A = comp ? B1 : B0;
      Frag a0 = ldfrag(A, GIDX(ti,0,lane), false);
      Frag a1 = ldfrag(A, GIDX(ti,1,lane), false);
      u32* O = comp ? B5 : pTXR;
#pragma unroll
      for (int tj=0;tj<4;++tj){
        Frag b0 = ldbg(UhFL, tj*2+0, lane);
        Frag b1 = ldbg(UhFL, tj*2+1, lane);
        f32x4 acc = {0.f,0.f,0.f,0.f};
        mfma4(a0,b0,acc); mfma4(a1,b1,acc);
        float xv[4] = {acc[0],acc[1],acc[2],acc[3]};
        store_tile(O, ti, tj, h, c15, xv);
      }
    }
    if (doTail){
      const int rb = w;               // row-block 0..7 of stacked [h2R;h2I]
      const int cb = rb&3;
      const u32* A = (rb<4) ? B2 : pH2I;
      Frag a0 = ldfrag(A, GIDX(cb,0,lane), false);
      Frag a1 = ldfrag(A, GIDX(cb,1,lane), false);
#pragma unroll
      for (int cz=0;cz<2;++cz){
        Frag b0 = ldbg(AB2FL, cz*2+0, lane);
        Frag b1 = ldbg(AB2FL, cz*2+1, lane);
        f32x4 za = {0.f,0.f,0.f,0.f};
        mfma4(a0,b0,za); mfma4(a1,b1,za);
        const int c = 16*cz + c15;
        if (c < 30){
          float* zp = Zt + c*129 + 16*rb + 4*h;
#pragma unroll
          for (int rr=0;rr<4;++rr) zp[rr] = za[rr];
        }
      }
    }
    __syncthreads();

    // ===== Phase 2: N1 = lam*outer(u) + (1-lam)*GEMM(T1,Uh); sumsq  + meas =
    if (doMain){
      const int comp = w>>2, ti = w&3;
      const u32* A = comp ? B5 : pTXR;
      Frag a0 = ldfrag(A, GIDX(ti,0,lane), false);
      Frag a1 = ldfrag(A, GIDX(ti,1,lane), false);
      u32* O = comp ? B8 : B7;
      float uR[4], uI[4];
#pragma unroll
      for (int rr=0;rr<4;++rr){
        uR[rr] = u_lds[16*ti + 4*h + rr];
        uI[rr] = u_lds[64 + 16*ti + 4*h + rr];
      }
      float ss = 0.f;
#pragma unroll
      for (int tj=0;tj<4;++tj){
        Frag b0 = ldbg(UhFL, tj*2+0, lane);
        Frag b1 = ldbg(UhFL, tj*2+1, lane);
        f32x4 acc = {0.f,0.f,0.f,0.f};
        mfma4(a0,b0,acc); mfma4(a1,b1,acc);
        const float urc = u_lds[16*tj + c15], uic = u_lds[64 + 16*tj + c15];
        float xv[4];
#pragma unroll
        for (int rr=0;rr<4;++rr){
          float ov = comp ? (uI[rr]*urc - uR[rr]*uic) : (uR[rr]*urc + uI[rr]*uic);
          xv[rr] = lam*ov + clm*acc[rr];
          ss = fmaf(xv[rr], xv[rr], ss);
        }
        store_tile(O, ti, tj, h, c15, xv);
      }
      ss = wave_sum(ss);
      if (lane == 0) scrN1[w] = ss;
    }
    if (doTail){
      {
        const int k = w;   // q_0..q_7
        float av = ABt[k*64 + lane], bv = ABt[(10+k)*64 + lane];
        float v = av*Zt[k*129 + lane] + bv*Zt[(10+k)*129 + lane]
                + av*Zt[(10+k)*129 + 64 + lane] - bv*Zt[k*129 + 64 + lane];
        v = wave_sum(v);
        if (lane == 0) scrQ[k] = v;
      }
      if (w < 2){
        const int k = 8 + w;
        float av = ABt[k*64 + lane], bv = ABt[(10+k)*64 + lane];
        float v = av*Zt[k*129 + lane] + bv*Zt[(10+k)*129 + lane]
                + av*Zt[(10+k)*129 + 64 + lane] - bv*Zt[k*129 + 64 + lane];
        v = wave_sum(v);
        if (lane == 0) scrQ[k] = v;
      } else if (w == 2){
        float v = 0.f;
#pragma unroll
        for (int cc=0; cc<10; ++cc)
          v = fmaf(ABt[(20+cc)*64 + lane], Zt[(20+cc)*129 + lane], v);
        v = wave_sum(v);
        if (lane == 0) scrQ[10] = v;
      }
    }
    __syncthreads();

    // ================= Phase 3: h1 = act(N1)  +  out(t-1) ==================
    if (doMain){
      const int o = w>>2, tj = w&3;
      f32x4 acc[4];
#pragma unroll
      for (int i=0;i<4;++i) acc[i] = f32x4{0.f,0.f,0.f,0.f};
#pragma unroll
      for (int m=0;m<2;++m){
        const u32* Ab = m ? B8 : B7;
        const u32* Bb = o ? (m ? B7 : B8) : (m ? B8 : B7);
        const bool neg = (o==1) && (m==1);
#pragma unroll
        for (int kc=0;kc<2;++kc){
          Frag bf = ldfrag(Bb, GIDX(tj,kc,lane), false);
#pragma unroll
          for (int i=0;i<4;++i){
            Frag af = ldfrag(Ab, GIDX(i,kc,lane), neg);
            mfma4(af, bf, acc[i]);
          }
        }
      }
      const f32x4* sv = reinterpret_cast<const f32x4*>(scrN1);
      f32x4 s4 = sv[0] + sv[1];
      const float trv = s4[0]+s4[1]+s4[2]+s4[3];
      const float sb = BETA_/trv, cbm = 1.f - BETA_;
      const u32* Nsrc = o ? B8 : B7;
      u32* Od = o ? B1 : B0;
#pragma unroll
      for (int i=0;i<4;++i){
        float n[4]; read_tile(Nsrc, i, tj, h, c15, n);
        float xv[4];
#pragma unroll
        for (int rr=0;rr<4;++rr) xv[rr] = fmaf(sb, acc[i][rr], cbm*n[rr]);
        store_tile(Od, i, tj, h, c15, xv);
      }
    }
    if (doTail && tid < 10){
      float pnum = dlam*scrQ[tid] + (1.f-dlam)*0.1f;
      float pden = dlam*scrQ[10] + (1.f-dlam);
      out[((size_t)bidx*T_ + (t-1))*C_ + tid] = logf(pnum/pden);
    }
    __syncthreads();

    if (doMain){
      // ============ Phase 4: TX = GEMM(h1,Ux), TH = GEMM(h2,Uh) ============
      {
        const int g2 = w>>2, comp=(w>>1)&1, th=w&1;   // ti in {th, th+2}
        const u32* A = g2 ? (comp? pH2I : B2) : (comp? B1 : B0);
        const u32* FL = g2 ? UhFL : UxFL;
        u32* O = g2 ? (comp? B7 : B6) : (comp? B5 : pTXR);
        Frag a00 = ldfrag(A, GIDX(th,0,lane),   false);
        Frag a01 = ldfrag(A, GIDX(th,1,lane),   false);
        Frag a10 = ldfrag(A, GIDX(th+2,0,lane), false);
        Frag a11 = ldfrag(A, GIDX(th+2,1,lane), false);
#pragma unroll
        for (int tj=0;tj<4;++tj){
          Frag b0 = ldbg(FL, tj*2+0, lane);
          Frag b1 = ldbg(FL, tj*2+1, lane);
          f32x4 acc0 = {0.f,0.f,0.f,0.f};
          mfma4(a00,b0,acc0); mfma4(a01,b1,acc0);
          float xv0[4] = {acc0[0],acc0[1],acc0[2],acc0[3]};
          store_tile(O, th, tj, h, c15, xv0);
          f32x4 acc1 = {0.f,0.f,0.f,0.f};
          mfma4(a10,b0,acc1); mfma4(a11,b1,acc1);
          float xv1[4] = {acc1[0],acc1[1],acc1[2],acc1[3]};
          store_tile(O, th+2, tj, h, c15, xv1);
        }
      }
      __syncthreads();

      // ====== Phase 5: N' = lam*GEMM(TX,Ux) + (1-lam)*GEMM(TH,Uh); sumsq ===
      {
        const int comp = w>>2, ti = w&3;
        u32* O = comp ? pH2I : B8;
        const u32* AX = comp ? B5 : pTXR;
        const u32* AH = comp ? B7 : B6;
        Frag ax0 = ldfrag(AX, GIDX(ti,0,lane), false);
        Frag ax1 = ldfrag(AX, GIDX(ti,1,lane), false);
        Frag ah0 = ldfrag(AH, GIDX(ti,0,lane), false);
        Frag ah1 = ldfrag(AH, GIDX(ti,1,lane), false);
        float ss = 0.f;
#pragma unroll
        for (int tj=0;tj<4;++tj){
          f32x4 aX = {0.f,0.f,0.f,0.f};
          {
            Frag bx0 = ldbg(UxFL, tj*2+0, lane);
            Frag bx1 = ldbg(UxFL, tj*2+1, lane);
            mfma4(ax0,bx0,aX); mfma4(ax1,bx1,aX);
          }
          f32x4 aH = {0.f,0.f,0.f,0.f};
          {
            Frag bh0 = ldbg(UhFL, tj*2+0, lane);
            Frag bh1 = ldbg(UhFL, tj*2+1, lane);
            mfma4(ah0,bh0,aH); mfma4(ah1,bh1,aH);
          }
          float xv[4];
#pragma unroll
          for (int rr=0;rr<4;++rr){
            xv[rr] = lam*aX[rr] + clm*aH[rr];
            ss = fmaf(xv[rr], xv[rr], ss);
          }
          store_tile(O, ti, tj, h, c15, xv);
        }
        ss = wave_sum(ss);
        if (lane == 0) scrNp[w] = ss;
      }
      __syncthreads();

      // ================= Phase 6: h2 = act(N') ==============================
      {
        const int o = w>>2, tj = w&3;
        const u32* NPR = B8;
        const u32* NPI = pH2I;
        f32x4 acc[4];
#pragma unroll
        for (int i=0;i<4;++i) acc[i] = f32x4{0.f,0.f,0.f,0.f};
#pragma unroll
        for (int m=0;m<2;++m){
          const u32* Ab = m ? NPI : NPR;
          const u32* Bb = o ? (m ? NPR : NPI) : (m ? NPI : NPR);
          const bool neg = (o==1) && (m==1);
#pragma unroll
          for (int kc=0;kc<2;++kc){
            Frag bf = ldfrag(Bb, GIDX(tj,kc,lane), false);
#pragma unroll
            for (int i=0;i<4;++i){
              Frag af = ldfrag(Ab, GIDX(i,kc,lane), neg);
              mfma4(af, bf, acc[i]);
            }
          }
        }
        const f32x4* sv = reinterpret_cast<const f32x4*>(scrNp);
        f32x4 s4 = sv[0] + sv[1];
        const float trv = s4[0]+s4[1]+s4[2]+s4[3];
        const float sb = BETA_/trv, cbm = 1.f - BETA_;
        const u32* Nsrc = o ? NPI : NPR;
        u32* Od = o ? pTXR : B2;    // h2 out: (B2, pTXR)
#pragma unroll
        for (int i=0;i<4;++i){
          float n[4]; read_tile(Nsrc, i, tj, h, c15, n);
          float xv[4];
#pragma unroll
          for (int rr=0;rr<4;++rr) xv[rr] = fmaf(sb, acc[i][rr], cbm*n[rr]);
          store_tile(Od, i, tj, h, c15, xv);
        }
      }
      __syncthreads();
    }
  }
}

extern "C" void kernel_launch(void* const* d_in, const int* in_sizes, int n_in,
                              void* d_out, int out_size, void* d_ws, size_t ws_size,
                              hipStream_t stream) {
    const float* x       = (const float*)d_in[0];
    const float* amp_w   = (const float*)d_in[1];
    const float* amp_b   = (const float*)d_in[2];
    const float* phase_w = (const float*)d_in[3];
    const float* phase_b = (const float*)d_in[4];
    const float* Ux      = (const float*)d_in[5];
    const float* Uh      = (const float*)d_in[6];
    const float* cl      = (const float*)d_in[7];
    const float* W       = (const float*)d_in[8];
    const float* dl      = (const float*)d_in[9];
    const float* meas    = (const float*)d_in[10];

    float* ws   = (float*)d_ws;
    float* u    = ws;                                  // 128*64*128 f32
    u32*  UhFL  = (u32*)(ws + 1048576);                // 4096
    u32*  UxFL  = UhFL + 4096;                         // 4096
    u32*  AB2FL = UxFL + 4096;                         // 2048
    float* AB2p = (float*)(AB2FL + 2048);              // 2048
    float* ABt  = AB2p + 2048;                         // 1920
    float* out  = (float*)d_out;

    proj_kernel<<<B_ * T_, 64, 0, stream>>>(x, amp_w, amp_b, phase_w, phase_b, Ux, u);
    setup_kernel<<<1, 256, 0, stream>>>(Uh, Ux, W, meas, UhFL, UxFL, AB2FL, AB2p, ABt);
    qrnn_kernel<<<B_, 512, 0, stream>>>(u, UhFL, UxFL, AB2FL, ABt, cl, dl, out);
}

// Round 8
// 1339.940 us; speedup vs baseline: 1.6117x; 1.2407x over previous
//
#include <hip/hip_runtime.h>
#include <math.h>

#define B_ 64
#define T_ 128
#define INDIM 300
#define D_ 64
#define C_ 10
#define BETA_ 0.8f

typedef unsigned int u32;
typedef _Float16 half8 __attribute__((ext_vector_type(8)));
typedef float f32x4 __attribute__((ext_vector_type(4)));
typedef u32 u32x4 __attribute__((ext_vector_type(4)));
typedef u32 u32x2 __attribute__((ext_vector_type(2)));

// fragment-group index: cb = 16-col block, kc = 32-k block
#define GIDX(cb,kc,ln) ((((cb)*2+(kc))*64) + (ln))

struct Frag { half8 h, l; };

static __device__ __forceinline__ float sigmoidf_(float x){ return 1.f/(1.f+expf(-x)); }

static __device__ __forceinline__ float wave_sum(float v){
#pragma unroll
  for (int off = 32; off > 0; off >>= 1) v += __shfl_down(v, off);
  return v;
}

static __device__ __forceinline__ u32 pkh(_Float16 a, _Float16 b){
  unsigned short ba = __builtin_bit_cast(unsigned short, a);
  unsigned short bb = __builtin_bit_cast(unsigned short, b);
  return (u32)ba | ((u32)bb << 16);
}

static __device__ __forceinline__ void split4(const float* x, u32x2& hw, u32x2& lw){
  _Float16 h0=(_Float16)x[0], h1=(_Float16)x[1], h2=(_Float16)x[2], h3=(_Float16)x[3];
  _Float16 l0=(_Float16)(x[0]-(float)h0), l1=(_Float16)(x[1]-(float)h1);
  _Float16 l2=(_Float16)(x[2]-(float)h2), l3=(_Float16)(x[3]-(float)h3);
  hw[0]=pkh(h0,h1); hw[1]=pkh(h2,h3); lw[0]=pkh(l0,l1); lw[1]=pkh(l2,l3);
}

static __device__ __forceinline__ void up2v(u32 hw, u32 lw, float& v0, float& v1){
  _Float16 h0=__builtin_bit_cast(_Float16,(unsigned short)(hw & 0xffffu));
  _Float16 h1=__builtin_bit_cast(_Float16,(unsigned short)(hw >> 16));
  _Float16 l0=__builtin_bit_cast(_Float16,(unsigned short)(lw & 0xffffu));
  _Float16 l1=__builtin_bit_cast(_Float16,(unsigned short)(lw >> 16));
  v0 = (float)h0 + (float)l0;
  v1 = (float)h1 + (float)l1;
}

// 3-term split product: (ah+al)(bh+bl) ~= ah*bh + ah*bl + al*bh.
static __device__ __forceinline__ void mfma4(const Frag& a, const Frag& b, f32x4& acc){
  acc = __builtin_amdgcn_mfma_f32_16x16x32_f16(a.h, b.h, acc, 0, 0, 0);
  acc = __builtin_amdgcn_mfma_f32_16x16x32_f16(a.h, b.l, acc, 0, 0, 0);
  acc = __builtin_amdgcn_mfma_f32_16x16x32_f16(a.l, b.h, acc, 0, 0, 0);
}

// same 3-term set with pinned bh and streamed bl (bl-use last: latency hidden)
static __device__ __forceinline__ void mfma3(const Frag& a, half8 bh, half8 bl, f32x4& acc){
  acc = __builtin_amdgcn_mfma_f32_16x16x32_f16(a.h, bh, acc, 0, 0, 0);
  acc = __builtin_amdgcn_mfma_f32_16x16x32_f16(a.l, bh, acc, 0, 0, 0);
  acc = __builtin_amdgcn_mfma_f32_16x16x32_f16(a.h, bl, acc, 0, 0, 0);
}

static __device__ __forceinline__ Frag ldfrag(const u32* buf, int g, bool neg){
  u32x4 a = *reinterpret_cast<const u32x4*>(buf + g*4);
  u32x4 b = *reinterpret_cast<const u32x4*>(buf + 2048 + g*4);
  if (neg){
#pragma unroll
    for (int i=0;i<4;++i){ a[i]^=0x80008000u; b[i]^=0x80008000u; }
  }
  Frag f; f.h = __builtin_bit_cast(half8, a); f.l = __builtin_bit_cast(half8, b);
  return f;
}

static __device__ __forceinline__ Frag ldbg(const u32* FL, int grp, int lane){
  const u32* p = FL + ((size_t)(grp*64 + lane))*8;
  u32x4 a = *reinterpret_cast<const u32x4*>(p);
  u32x4 b = *reinterpret_cast<const u32x4*>(p+4);
  Frag f; f.h = __builtin_bit_cast(half8, a); f.l = __builtin_bit_cast(half8, b);
  return f;
}

static __device__ __forceinline__ half8 ldbg_hi(const u32* FL, int grp, int lane){
  u32x4 a = *reinterpret_cast<const u32x4*>(FL + ((size_t)(grp*64 + lane))*8);
  return __builtin_bit_cast(half8, a);
}

static __device__ __forceinline__ half8 ldbg_lo(const u32* FL, int grp, int lane){
  u32x4 b = *reinterpret_cast<const u32x4*>(FL + ((size_t)(grp*64 + lane))*8 + 4);
  return __builtin_bit_cast(half8, b);
}

static __device__ __forceinline__ void store_tile(u32* O, int ti, int tj, int h, int c15,
                                                  const float* x){
  const int s = h & 1;
  const int lp = c15 + 16*((2*ti + (h>>1)) & 3);
  const int g = GIDX(tj, ti>>1, lp);
  u32x2 hw, lw; split4(x, hw, lw);
  *reinterpret_cast<u32x2*>(O + g*4 + 2*s) = hw;
  *reinterpret_cast<u32x2*>(O + 2048 + g*4 + 2*s) = lw;
}

static __device__ __forceinline__ void read_tile(const u32* O, int ti, int tj, int h, int c15,
                                                 float* n){
  const int s = h & 1;
  const int lp = c15 + 16*((2*ti + (h>>1)) & 3);
  const int g = GIDX(tj, ti>>1, lp);
  u32x2 nh = *reinterpret_cast<const u32x2*>(O + g*4 + 2*s);
  u32x2 nl = *reinterpret_cast<const u32x2*>(O + 2048 + g*4 + 2*s);
  up2v(nh[0],nl[0],n[0],n[1]); up2v(nh[1],nl[1],n[2],n[3]);
}

// ---------------- Kernel A: projections + s + u = Ux @ s -------------------
__global__ __launch_bounds__(64) void proj_kernel(
    const float* __restrict__ x, const float* __restrict__ amp_w,
    const float* __restrict__ amp_b, const float* __restrict__ phase_w,
    const float* __restrict__ phase_b, const float* __restrict__ Ux,
    float* __restrict__ u_out) {
    __shared__ float xr[INDIM];
    __shared__ float s_r[D_], s_i[D_];
    const int bt = blockIdx.x;
    const int b = bt / T_, t = bt % T_;
    const float* xrow = x + (size_t)bt * INDIM;
    for (int i = threadIdx.x; i < INDIM; i += 64) xr[i] = xrow[i];
    __syncthreads();
    const int d = threadIdx.x;
    float a = amp_b[d], p = phase_b[d];
    for (int k = 0; k < INDIM; ++k) {
        float xv = xr[k];
        a = fmaf(xv, amp_w[k * D_ + d], a);
        p = fmaf(xv, phase_w[k * D_ + d], p);
    }
    float sq = a * a;
    #pragma unroll
    for (int off = 32; off > 0; off >>= 1) sq += __shfl_xor(sq, off);
    float an = a / sqrtf(sq);
    s_r[d] = an * cosf(p);
    s_i[d] = an * sinf(p);
    __syncthreads();
    float ur = 0.f, ui = 0.f;
    const float* Uxrow = Ux + d * D_;
    for (int e = 0; e < D_; ++e) {
        float uv = Uxrow[e];
        ur = fmaf(uv, s_r[e], ur);
        ui = fmaf(uv, s_i[e], ui);
    }
    float* ub = u_out + ((size_t)t * B_ + b) * 128;
    ub[d] = ur;
    ub[64 + d] = ui;
}

// ---------------- Kernel B: operand-fragment precompute --------------------
__global__ __launch_bounds__(256) void setup_kernel(
    const float* __restrict__ Uh, const float* __restrict__ Ux,
    const float* __restrict__ W, const float* __restrict__ meas,
    u32* __restrict__ UhFL, u32* __restrict__ UxFL,
    u32* __restrict__ AB2FL, float* __restrict__ AB2p, float* __restrict__ ABt)
{
  const int tid = threadIdx.x;
  for (int wi = tid; wi < 4096; wi += 256){
    int off = wi & 7, g = wi >> 3;
    int lane_ = g & 63, cbkc = g >> 6;
    int cb = cbkc >> 1, kc = cbkc & 1;
    int wq = off & 3; bool isHi = off < 4;
    int k0 = 32*kc + 8*(lane_>>4) + 2*wq;
    int c  = 16*cb + (lane_&15);
    {
      float x0 = Uh[c*64 + k0], x1 = Uh[c*64 + k0 + 1];
      _Float16 h0=(_Float16)x0, h1=(_Float16)x1;
      UhFL[wi] = isHi ? pkh(h0,h1)
                      : pkh((_Float16)(x0-(float)h0), (_Float16)(x1-(float)h1));
    }
    {
      float x0 = Ux[c*64 + k0], x1 = Ux[c*64 + k0 + 1];
      _Float16 h0=(_Float16)x0, h1=(_Float16)x1;
      UxFL[wi] = isHi ? pkh(h0,h1)
                      : pkh((_Float16)(x0-(float)h0), (_Float16)(x1-(float)h1));
    }
  }
  __shared__ float invn[C_];
  if (tid < C_) {
    float s = 0.f;
    for (int j = 0; j < C_; ++j) {
      float vr = meas[(tid * C_ + j) * 2], vi = meas[(tid * C_ + j) * 2 + 1];
      s += vr * vr + vi * vi;
    }
    invn[tid] = 1.0f / sqrtf(s);
  }
  __syncthreads();
  for (int i = tid; i < D_ * 32; i += 256) {
    int dd = i >> 5, c = i & 31;
    float v = 0.f;
    if (c < C_) {
      float acc = 0.f;
      for (int j = 0; j < C_; ++j) acc = fmaf(W[dd * C_ + j], meas[(c * C_ + j) * 2], acc);
      v = acc * invn[c];
    } else if (c < 2 * C_) {
      int k = c - C_;
      float acc = 0.f;
      for (int j = 0; j < C_; ++j) acc = fmaf(W[dd * C_ + j], meas[(k * C_ + j) * 2 + 1], acc);
      v = acc * invn[k];
    } else if (c < 3 * C_) {
      v = W[dd * C_ + (c - 2 * C_)];
    }
    AB2p[i] = v;
  }
  __syncthreads();
  // AB2FL fragment layout
  for (int wi = tid; wi < 2048; wi += 256){
    int off = wi & 7, g = wi >> 3;
    int lane_ = g & 63, cbkc = g >> 6;
    int cb = cbkc >> 1, kc = cbkc & 1;
    int wq = off & 3; bool isHi = off < 4;
    int k0 = 32*kc + 8*(lane_>>4) + 2*wq;
    int c  = 16*cb + (lane_&15);
    float x0 = AB2p[k0*32 + c], x1 = AB2p[(k0+1)*32 + c];
    _Float16 h0=(_Float16)x0, h1=(_Float16)x1;
    AB2FL[wi] = isHi ? pkh(h0,h1)
                     : pkh((_Float16)(x0-(float)h0), (_Float16)(x1-(float)h1));
  }
  // ABt[c][d] = AB2p[d][c], c<30 (coalesced meas reads)
  for (int i = tid; i < 30*64; i += 256){
    int c = i >> 6, d = i & 63;
    ABt[i] = AB2p[d*32 + c];
  }
}

// ---------------- Kernel C: fused 2-layer scan + dense + measurement -------
// 512 threads / 8 waves: proven 128-VGPR config (1024-thread blocks are hard-
// capped at 64 VGPR -> spills; rounds 3-5). 2x2 wave tiling: wave owns a
// 32x32 block (2x2 of 16x16 tiles) => B-fragments restricted to 2 tj columns
// => Uh/Ux hi-halves pinned in 32 VGPRs; lo-halves streamed at point of use.
// Kills the 12K-cyc/step global-B pipe of the row-strip version.
__global__ __launch_bounds__(512) void qrnn_kernel(
    const float* __restrict__ u_in,
    const u32* __restrict__ UhFL, const u32* __restrict__ UxFL,
    const u32* __restrict__ AB2FL, const float* __restrict__ ABt,
    const float* __restrict__ cell_lambda, const float* __restrict__ dense_lambda,
    float* __restrict__ out)
{
  // 9 matrix buffers, each 4096 u32 (hi 2048 | lo 2048)
  __shared__ __align__(16) u32 ds[9*4096];
  __shared__ float u_lds[128];
  __shared__ float scrN1[8], scrNp[8], scrQ[12];

  const int tid = threadIdx.x;
  const int lane = tid & 63;
  const int w = tid >> 6;          // 0..7
  const int h = lane >> 4;
  const int c15 = lane & 15;
  const int bidx = blockIdx.x;
  const float lam = sigmoidf_(cell_lambda[0]);
  const float clm = 1.f - lam;
  const float dlam = sigmoidf_(dense_lambda[0]);

  // 2x2 tiling coordinates
  const int comp = w >> 2;         // 0: real, 1: imag
  const int q = w & 3;
  const int hi2 = q >> 1;          // ti in {2*hi2, 2*hi2+1}
  const int hj2 = q & 1;           // tj in {2*hj2, 2*hj2+1}
  const int ti0 = 2*hi2, tj0 = 2*hj2;

  u32* const B0 = ds + 0*4096;   // h1R
  u32* const B1 = ds + 1*4096;   // h1I
  u32* const B2 = ds + 2*4096;   // h2R (fixed)
  u32* const B3 = ds + 3*4096;
  u32* const B4 = ds + 4*4096;
  u32* const B5 = ds + 5*4096;   // T1I / TXI
  u32* const B6 = ds + 6*4096;   // Zt (fp32 30x129) / THR
  u32* const B7 = ds + 7*4096;   // N1R / THI
  u32* const B8 = ds + 8*4096;   // N1I / N'R
  float* const Zt = reinterpret_cast<float*>(B6);

  // ---- pinned B-fragment hi-halves: Uh, Ux for this wave's tj pair ----
  half8 UhPh[2][2], UxPh[2][2];    // [tjj][kc] : 32 VGPRs total
#pragma unroll
  for (int tjj=0;tjj<2;++tjj)
#pragma unroll
    for (int kc=0;kc<2;++kc){
      UhPh[tjj][kc] = ldbg_hi(UhFL, (tj0+tjj)*2+kc, lane);
      UxPh[tjj][kc] = ldbg_hi(UxFL, (tj0+tjj)*2+kc, lane);
    }

  // ---- init h1 = h2 = I/64 ----
  const u32 one64 = (u32)__builtin_bit_cast(unsigned short, (_Float16)0.015625f);
  for (int wi = tid; wi < 4096; wi += 512){
    u32 vR = 0u;
    if (wi < 2048){
      int g = wi >> 2, wq = wi & 3;
      int lane_ = g & 63, cbkc = g >> 6;
      int cb = cbkc >> 1, kc = cbkc & 1;
      int k0 = 32*kc + 8*(lane_>>4) + 2*wq;
      int c = 16*cb + (lane_&15);
      if (k0 == c)   vR |= one64;
      if (k0+1 == c) vR |= (one64 << 16);
    }
    B0[wi] = vR; B2[wi] = vR; B1[wi] = 0u; B3[wi] = 0u;
  }
  __syncthreads();

  for (int t = 0; t <= T_; ++t){
    const bool doMain = (t < T_);
    const bool doTail = (t > 0);
    const int par = t & 1;
    u32* const pH2I = par ? B4 : B3;   // h2I in-state; also N' I dest
    u32* const pTXR = par ? B3 : B4;   // T1R/TXR dest; also h2I out-state

    // ================= Phase 1: T1 = GEMM(h1,Uh)  +  dense(t-1) ===========
    if (doMain){
      if (tid < 128) u_lds[tid] = u_in[((size_t)t*B_ + bidx)*128 + tid];
      const u32* A = comp ? B1 : B0;
      u32* O = comp ? B5 : pTXR;
      f32x4 acc[2][2];
#pragma unroll
      for (int i=0;i<2;++i)
#pragma unroll
        for (int j=0;j<2;++j) acc[i][j] = f32x4{0.f,0.f,0.f,0.f};
#pragma unroll
      for (int kc=0;kc<2;++kc){
        Frag a0 = ldfrag(A, GIDX(ti0,  kc, lane), false);
        Frag a1 = ldfrag(A, GIDX(ti0+1,kc, lane), false);
#pragma unroll
        for (int tjj=0;tjj<2;++tjj){
          half8 bl = ldbg_lo(UhFL, (tj0+tjj)*2+kc, lane);
          mfma3(a0, UhPh[tjj][kc], bl, acc[0][tjj]);
          mfma3(a1, UhPh[tjj][kc], bl, acc[1][tjj]);
        }
      }
#pragma unroll
      for (int i=0;i<2;++i)
#pragma unroll
        for (int j=0;j<2;++j){
          float xv[4] = {acc[i][j][0],acc[i][j][1],acc[i][j][2],acc[i][j][3]};
          store_tile(O, ti0+i, tj0+j, h, c15, xv);
        }
    }
    if (doTail){
      const int rb = w;               // row-block 0..7 of stacked [h2R;h2I]
      const int cb = rb&3;
      const u32* A = (rb<4) ? B2 : pH2I;
      Frag a0 = ldfrag(A, GIDX(cb,0,lane), false);
      Frag a1 = ldfrag(A, GIDX(cb,1,lane), false);
#pragma unroll
      for (int cz=0;cz<2;++cz){
        Frag b0 = ldbg(AB2FL, cz*2+0, lane);
        Frag b1 = ldbg(AB2FL, cz*2+1, lane);
        f32x4 za = {0.f,0.f,0.f,0.f};
        mfma4(a0,b0,za); mfma4(a1,b1,za);
        const int c = 16*cz + c15;
        if (c < 30){
          float* zp = Zt + c*129 + 16*rb + 4*h;
#pragma unroll
          for (int rr=0;rr<4;++rr) zp[rr] = za[rr];
        }
      }
    }
    __syncthreads();

    // ===== Phase 2: N1 = lam*outer(u) + (1-lam)*GEMM(T1,Uh); sumsq  + meas =
    if (doMain){
      const u32* A = comp ? B5 : pTXR;
      u32* O = comp ? B8 : B7;
      f32x4 acc[2][2];
#pragma unroll
      for (int i=0;i<2;++i)
#pragma unroll
        for (int j=0;j<2;++j) acc[i][j] = f32x4{0.f,0.f,0.f,0.f};
#pragma unroll
      for (int kc=0;kc<2;++kc){
        Frag a0 = ldfrag(A, GIDX(ti0,  kc, lane), false);
        Frag a1 = ldfrag(A, GIDX(ti0+1,kc, lane), false);
#pragma unroll
        for (int tjj=0;tjj<2;++tjj){
          half8 bl = ldbg_lo(UhFL, (tj0+tjj)*2+kc, lane);
          mfma3(a0, UhPh[tjj][kc], bl, acc[0][tjj]);
          mfma3(a1, UhPh[tjj][kc], bl, acc[1][tjj]);
        }
      }
      float ss = 0.f;
#pragma unroll
      for (int i=0;i<2;++i){
        const int ti = ti0+i;
        float uR[4], uI[4];
#pragma unroll
        for (int rr=0;rr<4;++rr){
          uR[rr] = u_lds[16*ti + 4*h + rr];
          uI[rr] = u_lds[64 + 16*ti + 4*h + rr];
        }
#pragma unroll
        for (int j=0;j<2;++j){
          const int tj = tj0+j;
          const float urc = u_lds[16*tj + c15], uic = u_lds[64 + 16*tj + c15];
          float xv[4];
#pragma unroll
          for (int rr=0;rr<4;++rr){
            float ov = comp ? (uI[rr]*urc - uR[rr]*uic) : (uR[rr]*urc + uI[rr]*uic);
            xv[rr] = lam*ov + clm*acc[i][j][rr];
            ss = fmaf(xv[rr], xv[rr], ss);
          }
          store_tile(O, ti, tj, h, c15, xv);
        }
      }
      ss = wave_sum(ss);
      if (lane == 0) scrN1[w] = ss;
    }
    if (doTail){
      {
        const int k = w;   // q_0..q_7
        float av = ABt[k*64 + lane], bv = ABt[(10+k)*64 + lane];
        float v = av*Zt[k*129 + lane] + bv*Zt[(10+k)*129 + lane]
                + av*Zt[(10+k)*129 + 64 + lane] - bv*Zt[k*129 + 64 + lane];
        v = wave_sum(v);
        if (lane == 0) scrQ[k] = v;
      }
      if (w < 2){
        const int k = 8 + w;
        float av = ABt[k*64 + lane], bv = ABt[(10+k)*64 + lane];
        float v = av*Zt[k*129 + lane] + bv*Zt[(10+k)*129 + lane]
                + av*Zt[(10+k)*129 + 64 + lane] - bv*Zt[k*129 + 64 + lane];
        v = wave_sum(v);
        if (lane == 0) scrQ[k] = v;
      } else if (w == 2){
        float v = 0.f;
#pragma unroll
        for (int cc=0; cc<10; ++cc)
          v = fmaf(ABt[(20+cc)*64 + lane], Zt[(20+cc)*129 + lane], v);
        v = wave_sum(v);
        if (lane == 0) scrQ[10] = v;
      }
    }
    __syncthreads();

    // ================= Phase 3: h1 = act(N1)  +  out(t-1) ==================
    if (doMain){
      const int o = comp;
      f32x4 acc[2][2];
#pragma unroll
      for (int i=0;i<2;++i)
#pragma unroll
        for (int j=0;j<2;++j) acc[i][j] = f32x4{0.f,0.f,0.f,0.f};
#pragma unroll
      for (int m=0;m<2;++m){
        const u32* Ab = m ? B8 : B7;
        const u32* Bb = o ? (m ? B7 : B8) : (m ? B8 : B7);
        const bool neg = (o==1) && (m==1);
#pragma unroll
        for (int kc=0;kc<2;++kc){
          Frag a0 = ldfrag(Ab, GIDX(ti0,  kc, lane), neg);
          Frag a1 = ldfrag(Ab, GIDX(ti0+1,kc, lane), neg);
          Frag b0 = ldfrag(Bb, GIDX(tj0,  kc, lane), false);
          Frag b1 = ldfrag(Bb, GIDX(tj0+1,kc, lane), false);
          mfma4(a0,b0,acc[0][0]); mfma4(a0,b1,acc[0][1]);
          mfma4(a1,b0,acc[1][0]); mfma4(a1,b1,acc[1][1]);
        }
      }
      const f32x4* sv = reinterpret_cast<const f32x4*>(scrN1);
      f32x4 s4 = sv[0] + sv[1];
      const float trv = s4[0]+s4[1]+s4[2]+s4[3];
      const float sb = BETA_/trv, cbm = 1.f - BETA_;
      const u32* Nsrc = o ? B8 : B7;
      u32* Od = o ? B1 : B0;
#pragma unroll
      for (int i=0;i<2;++i)
#pragma unroll
        for (int j=0;j<2;++j){
          float n[4]; read_tile(Nsrc, ti0+i, tj0+j, h, c15, n);
          float xv[4];
#pragma unroll
          for (int rr=0;rr<4;++rr) xv[rr] = fmaf(sb, acc[i][j][rr], cbm*n[rr]);
          store_tile(Od, ti0+i, tj0+j, h, c15, xv);
        }
    }
    if (doTail && tid < 10){
      float pnum = dlam*scrQ[tid] + (1.f-dlam)*0.1f;
      float pden = dlam*scrQ[10] + (1.f-dlam);
      out[((size_t)bidx*T_ + (t-1))*C_ + tid] = logf(pnum/pden);
    }
    __syncthreads();

    if (doMain){
      // ======= Phase 4: TX = GEMM(h1,Ux) and TH = GEMM(h2,Uh), per wave ====
      {
        f32x4 acc[2][2];
        // --- TX = h1 * Ux ---
        const u32* A1 = comp ? B1 : B0;
        u32* O1 = comp ? B5 : pTXR;
#pragma unroll
        for (int i=0;i<2;++i)
#pragma unroll
          for (int j=0;j<2;++j) acc[i][j] = f32x4{0.f,0.f,0.f,0.f};
#pragma unroll
        for (int kc=0;kc<2;++kc){
          Frag a0 = ldfrag(A1, GIDX(ti0,  kc, lane), false);
          Frag a1 = ldfrag(A1, GIDX(ti0+1,kc, lane), false);
#pragma unroll
          for (int tjj=0;tjj<2;++tjj){
            half8 bl = ldbg_lo(UxFL, (tj0+tjj)*2+kc, lane);
            mfma3(a0, UxPh[tjj][kc], bl, acc[0][tjj]);
            mfma3(a1, UxPh[tjj][kc], bl, acc[1][tjj]);
          }
        }
#pragma unroll
        for (int i=0;i<2;++i)
#pragma unroll
          for (int j=0;j<2;++j){
            float xv[4] = {acc[i][j][0],acc[i][j][1],acc[i][j][2],acc[i][j][3]};
            store_tile(O1, ti0+i, tj0+j, h, c15, xv);
          }
        // --- TH = h2 * Uh ---
        const u32* A2 = comp ? pH2I : B2;
        u32* O2 = comp ? B7 : B6;
#pragma unroll
        for (int i=0;i<2;++i)
#pragma unroll
          for (int j=0;j<2;++j) acc[i][j] = f32x4{0.f,0.f,0.f,0.f};
#pragma unroll
        for (int kc=0;kc<2;++kc){
          Frag a0 = ldfrag(A2, GIDX(ti0,  kc, lane), false);
          Frag a1 = ldfrag(A2, GIDX(ti0+1,kc, lane), false);
#pragma unroll
          for (int tjj=0;tjj<2;++tjj){
            half8 bl = ldbg_lo(UhFL, (tj0+tjj)*2+kc, lane);
            mfma3(a0, UhPh[tjj][kc], bl, acc[0][tjj]);
            mfma3(a1, UhPh[tjj][kc], bl, acc[1][tjj]);
          }
        }
#pragma unroll
        for (int i=0;i<2;++i)
#pragma unroll
          for (int j=0;j<2;++j){
            float xv[4] = {acc[i][j][0],acc[i][j][1],acc[i][j][2],acc[i][j][3]};
            store_tile(O2, ti0+i, tj0+j, h, c15, xv);
          }
      }
      __syncthreads();

      // ====== Phase 5: N' = lam*GEMM(TX,Ux) + (1-lam)*GEMM(TH,Uh); sumsq ===
      {
        u32* O = comp ? pH2I : B8;
        const u32* AX = comp ? B5 : pTXR;
        const u32* AH = comp ? B7 : B6;
        f32x4 aXc[2][2], aHc[2][2];
#pragma unroll
        for (int i=0;i<2;++i)
#pragma unroll
          for (int j=0;j<2;++j){ aXc[i][j]=f32x4{0.f,0.f,0.f,0.f}; aHc[i][j]=f32x4{0.f,0.f,0.f,0.f}; }
#pragma unroll
        for (int kc=0;kc<2;++kc){
          {
            Frag x0 = ldfrag(AX, GIDX(ti0,  kc, lane), false);
            Frag x1 = ldfrag(AX, GIDX(ti0+1,kc, lane), false);
#pragma unroll
            for (int tjj=0;tjj<2;++tjj){
              half8 bl = ldbg_lo(UxFL, (tj0+tjj)*2+kc, lane);
              mfma3(x0, UxPh[tjj][kc], bl, aXc[0][tjj]);
              mfma3(x1, UxPh[tjj][kc], bl, aXc[1][tjj]);
            }
          }
          {
            Frag h0f = ldfrag(AH, GIDX(ti0,  kc, lane), false);
            Frag h1f = ldfrag(AH, GIDX(ti0+1,kc, lane), false);
#pragma unroll
            for (int tjj=0;tjj<2;++tjj){
              half8 bl = ldbg_lo(UhFL, (tj0+tjj)*2+kc, lane);
              mfma3(h0f, UhPh[tjj][kc], bl, aHc[0][tjj]);
              mfma3(h1f, UhPh[tjj][kc], bl, aHc[1][tjj]);
            }
          }
        }
        float ss = 0.f;
#pragma unroll
        for (int i=0;i<2;++i)
#pragma unroll
          for (int j=0;j<2;++j){
            float xv[4];
#pragma unroll
            for (int rr=0;rr<4;++rr){
              xv[rr] = lam*aXc[i][j][rr] + clm*aHc[i][j][rr];
              ss = fmaf(xv[rr], xv[rr], ss);
            }
            store_tile(O, ti0+i, tj0+j, h, c15, xv);
          }
        ss = wave_sum(ss);
        if (lane == 0) scrNp[w] = ss;
      }
      __syncthreads();

      // ================= Phase 6: h2 = act(N') ==============================
      {
        const int o = comp;
        const u32* NPR = B8;
        const u32* NPI = pH2I;
        f32x4 acc[2][2];
#pragma unroll
        for (int i=0;i<2;++i)
#pragma unroll
          for (int j=0;j<2;++j) acc[i][j] = f32x4{0.f,0.f,0.f,0.f};
#pragma unroll
        for (int m=0;m<2;++m){
          const u32* Ab = m ? NPI : NPR;
          const u32* Bb = o ? (m ? NPR : NPI) : (m ? NPI : NPR);
          const bool neg = (o==1) && (m==1);
#pragma unroll
          for (int kc=0;kc<2;++kc){
            Frag a0 = ldfrag(Ab, GIDX(ti0,  kc, lane), neg);
            Frag a1 = ldfrag(Ab, GIDX(ti0+1,kc, lane), neg);
            Frag b0 = ldfrag(Bb, GIDX(tj0,  kc, lane), false);
            Frag b1 = ldfrag(Bb, GIDX(tj0+1,kc, lane), false);
            mfma4(a0,b0,acc[0][0]); mfma4(a0,b1,acc[0][1]);
            mfma4(a1,b0,acc[1][0]); mfma4(a1,b1,acc[1][1]);
          }
        }
        const f32x4* sv = reinterpret_cast<const f32x4*>(scrNp);
        f32x4 s4 = sv[0] + sv[1];
        const float trv = s4[0]+s4[1]+s4[2]+s4[3];
        const float sb = BETA_/trv, cbm = 1.f - BETA_;
        const u32* Nsrc = o ? NPI : NPR;
        u32* Od = o ? pTXR : B2;    // h2 out: (B2, pTXR)
#pragma unroll
        for (int i=0;i<2;++i)
#pragma unroll
          for (int j=0;j<2;++j){
            float n[4]; read_tile(Nsrc, ti0+i, tj0+j, h, c15, n);
            float xv[4];
#pragma unroll
            for (int rr=0;rr<4;++rr) xv[rr] = fmaf(sb, acc[i][j][rr], cbm*n[rr]);
            store_tile(Od, ti0+i, tj0+j, h, c15, xv);
          }
      }
      __syncthreads();
    }
  }
}

extern "C" void kernel_launch(void* const* d_in, const int* in_sizes, int n_in,
                              void* d_out, int out_size, void* d_ws, size_t ws_size,
                              hipStream_t stream) {
    const float* x       = (const float*)d_in[0];
    const float* amp_w   = (const float*)d_in[1];
    const float* amp_b   = (const float*)d_in[2];
    const float* phase_w = (const float*)d_in[3];
    const float* phase_b = (const float*)d_in[4];
    const float* Ux      = (const float*)d_in[5];
    const float* Uh      = (const float*)d_in[6];
    const float* cl      = (const float*)d_in[7];
    const float* W       = (const float*)d_in[8];
    const float* dl      = (const float*)d_in[9];
    const float* meas    = (const float*)d_in[10];

    float* ws   = (float*)d_ws;
    float* u    = ws;                                  // 128*64*128 f32
    u32*  UhFL  = (u32*)(ws + 1048576);                // 4096
    u32*  UxFL  = UhFL + 4096;                         // 4096
    u32*  AB2FL = UxFL + 4096;                         // 2048
    float* AB2p = (float*)(AB2FL + 2048);              // 2048
    float* ABt  = AB2p + 2048;                         // 1920
    float* out  = (float*)d_out;

    proj_kernel<<<B_ * T_, 64, 0, stream>>>(x, amp_w, amp_b, phase_w, phase_b, Ux, u);
    setup_kernel<<<1, 256, 0, stream>>>(Uh, Ux, W, meas, UhFL, UxFL, AB2FL, AB2p, ABt);
    qrnn_kernel<<<B_, 512, 0, stream>>>(u, UhFL, UxFL, AB2FL, ABt, cl, dl, out);
}